// Round 1
// baseline (1225.817 us; speedup 1.0000x reference)
//
#include <hip/hip_runtime.h>

// Problem constants (match reference setup_inputs)
constexpr int N_NODES = 50000;
constexpr int N_EDGES = 800000;
constexpr int N_ETOT  = N_EDGES + N_NODES;   // with self loops
constexpr int HID     = 128;
constexpr int HEADS   = 4;
constexpr int ED      = 12;
constexpr int LAYERS  = 4;
constexpr float BN_EPS = 1e-5f;

// ---------------------------------------------------------------------------
// CSR build: histogram of dst, single-block scan, scatter
// ---------------------------------------------------------------------------
__global__ void hist_kernel(const int* __restrict__ dst, int* __restrict__ hist) {
    int e = blockIdx.x * blockDim.x + threadIdx.x;
    if (e >= N_ETOT) return;
    int d = (e < N_EDGES) ? dst[e] : (e - N_EDGES);
    atomicAdd(&hist[d], 1);
}

__global__ void scan_kernel(const int* __restrict__ hist, int* __restrict__ rowp,
                            int* __restrict__ cursor) {
    __shared__ int sdata[1024];
    const int CPB = (N_NODES + 1023) / 1024;  // 49
    int t = threadIdx.x;
    int base = t * CPB;
    int local = 0;
    for (int j = 0; j < CPB; j++) {
        int n = base + j;
        if (n < N_NODES) local += hist[n];
    }
    sdata[t] = local;
    __syncthreads();
    for (int off = 1; off < 1024; off <<= 1) {
        int v = (t >= off) ? sdata[t - off] : 0;
        __syncthreads();
        sdata[t] += v;
        __syncthreads();
    }
    int run = sdata[t] - local;  // exclusive
    for (int j = 0; j < CPB; j++) {
        int n = base + j;
        if (n < N_NODES) {
            rowp[n] = run;
            cursor[n] = run;
            run += hist[n];
        }
    }
    if (t == 1023) rowp[N_NODES] = sdata[1023];
}

__global__ void scatter_kernel(const int* __restrict__ src, const int* __restrict__ dst,
                               int* __restrict__ cursor, int* __restrict__ csr_eid,
                               int* __restrict__ csr_src) {
    int e = blockIdx.x * blockDim.x + threadIdx.x;
    if (e >= N_ETOT) return;
    int s, d;
    if (e < N_EDGES) { s = src[e]; d = dst[e]; }
    else             { s = d = e - N_EDGES; }
    int pos = atomicAdd(&cursor[d], 1);
    csr_eid[pos] = e;
    csr_src[pos] = s;
}

// ---------------------------------------------------------------------------
// edge_attr mean (over real edges) -> easum[12]
// ---------------------------------------------------------------------------
__launch_bounds__(256)
__global__ void eamean_kernel(const float* __restrict__ ea, float* __restrict__ easum) {
    __shared__ float ls[12];
    int t = threadIdx.x;
    if (t < 12) ls[t] = 0.f;
    __syncthreads();
    float loc[12];
#pragma unroll
    for (int d = 0; d < 12; d++) loc[d] = 0.f;
    int stride = gridDim.x * 256;
    for (int e = blockIdx.x * 256 + t; e < N_EDGES; e += stride) {
        const float* er = ea + (size_t)e * ED;
#pragma unroll
        for (int d = 0; d < 12; d++) loc[d] += er[d];
    }
#pragma unroll
    for (int d = 0; d < 12; d++) atomicAdd(&ls[d], loc[d]);
    __syncthreads();
    if (t < 12) atomicAdd(&easum[t], ls[t]);
}

// Precompute per-layer Wea[12][4] (= We folded with att_edge) and self-loop
// attention contribution aloop[4] = ea_mean @ Wea.
__global__ void prep_kernel(const float* __restrict__ easum, const float* __restrict__ We,
                            const float* __restrict__ att_edge, float* __restrict__ wea_all,
                            float* __restrict__ aloop) {
    __shared__ float em[12];
    __shared__ float weash[LAYERS * ED * HEADS];  // 192
    int t = threadIdx.x;
    if (t < 12) em[t] = easum[t] / (float)N_EDGES;
    if (t < LAYERS * ED * HEADS) {
        int l = t / (ED * HEADS);
        int r = t % (ED * HEADS);
        int d = r / HEADS;
        int h = r % HEADS;
        float sum = 0.f;
#pragma unroll
        for (int c = 0; c < 32; c++)
            sum += We[((size_t)(l * ED + d)) * HID + h * 32 + c] *
                   att_edge[(l * HEADS + h) * 32 + c];
        wea_all[t] = sum;
        weash[t] = sum;
    }
    __syncthreads();
    if (t < LAYERS * HEADS) {
        int l = t / HEADS, h = t % HEADS;
        float s = 0.f;
#pragma unroll
        for (int d = 0; d < 12; d++) s += em[d] * weash[l * ED * HEADS + d * HEADS + h];
        aloop[t] = s;
    }
}

// ---------------------------------------------------------------------------
// GEMM: C[M,128] = A[M,K] @ B[K,128] (+bias, relu optional). B staged in LDS.
// Block: 256 threads -> 64 rows x 128 cols; thread: 4 rows x 8 cols.
// ---------------------------------------------------------------------------
template <int K>
__launch_bounds__(256)
__global__ void gemm_kernel(const float* __restrict__ A, const float* __restrict__ B,
                            const float* __restrict__ bias, float* __restrict__ C,
                            int M, int fuse_relu) {
    __shared__ float Bs[K * 128];
    int t = threadIdx.x;
    const float4* B4 = (const float4*)B;
    float4* Bs4 = (float4*)Bs;
#pragma unroll
    for (int i = t; i < K * 32; i += 256) Bs4[i] = B4[i];
    __syncthreads();

    int c0 = (t & 15) * 8;
    int r0 = (t >> 4) * 4;
    int rbase = blockIdx.x * 64 + r0;

    float acc[4][8];
#pragma unroll
    for (int j = 0; j < 4; j++)
#pragma unroll
        for (int c = 0; c < 8; c++) acc[j][c] = 0.f;

    const float4* A4 = (const float4*)A;
    int rg[4];
#pragma unroll
    for (int j = 0; j < 4; j++) rg[j] = min(rbase + j, M - 1);

    for (int kk = 0; kk < K; kk += 4) {
        float4 av[4];
#pragma unroll
        for (int j = 0; j < 4; j++) av[j] = A4[(size_t)rg[j] * (K / 4) + (kk >> 2)];
        float a_arr[4][4];
#pragma unroll
        for (int j = 0; j < 4; j++) {
            a_arr[j][0] = av[j].x; a_arr[j][1] = av[j].y;
            a_arr[j][2] = av[j].z; a_arr[j][3] = av[j].w;
        }
#pragma unroll
        for (int jj = 0; jj < 4; jj++) {
            float4 b0 = Bs4[(kk + jj) * 32 + (c0 >> 2)];
            float4 b1 = Bs4[(kk + jj) * 32 + (c0 >> 2) + 1];
#pragma unroll
            for (int j = 0; j < 4; j++) {
                float a = a_arr[j][jj];
                acc[j][0] += a * b0.x; acc[j][1] += a * b0.y;
                acc[j][2] += a * b0.z; acc[j][3] += a * b0.w;
                acc[j][4] += a * b1.x; acc[j][5] += a * b1.y;
                acc[j][6] += a * b1.z; acc[j][7] += a * b1.w;
            }
        }
    }

#pragma unroll
    for (int j = 0; j < 4; j++) {
        int r = rbase + j;
        if (r < M) {
            float4 o0, o1;
            o0.x = acc[j][0]; o0.y = acc[j][1]; o0.z = acc[j][2]; o0.w = acc[j][3];
            o1.x = acc[j][4]; o1.y = acc[j][5]; o1.z = acc[j][6]; o1.w = acc[j][7];
            if (bias) {
                o0.x += bias[c0 + 0]; o0.y += bias[c0 + 1];
                o0.z += bias[c0 + 2]; o0.w += bias[c0 + 3];
                o1.x += bias[c0 + 4]; o1.y += bias[c0 + 5];
                o1.z += bias[c0 + 6]; o1.w += bias[c0 + 7];
            }
            if (fuse_relu) {
                o0.x = fmaxf(o0.x, 0.f); o0.y = fmaxf(o0.y, 0.f);
                o0.z = fmaxf(o0.z, 0.f); o0.w = fmaxf(o0.w, 0.f);
                o1.x = fmaxf(o1.x, 0.f); o1.y = fmaxf(o1.y, 0.f);
                o1.z = fmaxf(o1.z, 0.f); o1.w = fmaxf(o1.w, 0.f);
            }
            ((float4*)(C + (size_t)r * 128 + c0))[0] = o0;
            ((float4*)(C + (size_t)r * 128 + c0 + 4))[0] = o1;
        }
    }
}

// ---------------------------------------------------------------------------
// Per-node attention dot products: a_src[n,h], a_dst[n,h]
// ---------------------------------------------------------------------------
__global__ void attdot_kernel(const float* __restrict__ xp, const float* __restrict__ att_s,
                              const float* __restrict__ att_d, float* __restrict__ asrc,
                              float* __restrict__ adst) {
    int n = blockIdx.x * blockDim.x + threadIdx.x;
    if (n >= N_NODES) return;
    const float4* x4 = (const float4*)(xp + (size_t)n * 128);
    const float4* s4 = (const float4*)att_s;
    const float4* d4 = (const float4*)att_d;
    float rs[4], rd[4];
#pragma unroll
    for (int h = 0; h < 4; h++) {
        float ss = 0.f, dd = 0.f;
#pragma unroll
        for (int q = 0; q < 8; q++) {
            float4 v = x4[h * 8 + q];
            float4 a = s4[h * 8 + q];
            float4 b = d4[h * 8 + q];
            ss += v.x * a.x + v.y * a.y + v.z * a.z + v.w * a.w;
            dd += v.x * b.x + v.y * b.y + v.z * b.z + v.w * b.w;
        }
        rs[h] = ss; rd[h] = dd;
    }
    ((float4*)asrc)[n] = make_float4(rs[0], rs[1], rs[2], rs[3]);
    ((float4*)adst)[n] = make_float4(rd[0], rd[1], rd[2], rd[3]);
}

// ---------------------------------------------------------------------------
// Per-edge attention logits (leaky-relu'd), stored [E',4]
// ---------------------------------------------------------------------------
__launch_bounds__(256)
__global__ void edge_kernel(const int* __restrict__ src, const int* __restrict__ dst,
                            const float* __restrict__ ea, const float* __restrict__ asrc,
                            const float* __restrict__ adst, const float* __restrict__ wea,
                            const float* __restrict__ aloop, float* __restrict__ aex) {
    int e = blockIdx.x * blockDim.x + threadIdx.x;
    if (e >= N_ETOT) return;
    int s, d;
    float ae0, ae1, ae2, ae3;
    if (e < N_EDGES) {
        s = src[e]; d = dst[e];
        ae0 = ae1 = ae2 = ae3 = 0.f;
        const float* er = ea + (size_t)e * ED;
#pragma unroll
        for (int dd = 0; dd < 12; dd++) {
            float v = er[dd];
            ae0 += v * wea[dd * 4 + 0];
            ae1 += v * wea[dd * 4 + 1];
            ae2 += v * wea[dd * 4 + 2];
            ae3 += v * wea[dd * 4 + 3];
        }
    } else {
        s = d = e - N_EDGES;
        ae0 = aloop[0]; ae1 = aloop[1]; ae2 = aloop[2]; ae3 = aloop[3];
    }
    float4 as = ((const float4*)asrc)[s];
    float4 ad = ((const float4*)adst)[d];
    float a0 = as.x + ad.x + ae0;
    float a1 = as.y + ad.y + ae1;
    float a2 = as.z + ad.z + ae2;
    float a3 = as.w + ad.w + ae3;
    a0 = (a0 > 0.f) ? a0 : 0.2f * a0;
    a1 = (a1 > 0.f) ? a1 : 0.2f * a1;
    a2 = (a2 > 0.f) ? a2 : 0.2f * a2;
    a3 = (a3 > 0.f) ? a3 : 0.2f * a3;
    ((float4*)aex)[e] = make_float4(a0, a1, a2, a3);
}

// ---------------------------------------------------------------------------
// Per-destination-node softmax + message aggregation. One wave (64 lanes) per
// node: lanes 0..63 own channels 2*lane, 2*lane+1. No atomics anywhere.
// ---------------------------------------------------------------------------
__launch_bounds__(256)
__global__ void node_kernel(const float* __restrict__ aex, const int* __restrict__ rowp,
                            const int* __restrict__ csr_eid, const int* __restrict__ csr_src,
                            const float* __restrict__ xp, float* __restrict__ out) {
    int gw = (blockIdx.x * blockDim.x + threadIdx.x) >> 6;
    int lane = threadIdx.x & 63;
    if (gw >= N_NODES) return;
    int beg = rowp[gw], end = rowp[gw + 1];
    const float4* aex4 = (const float4*)aex;

    // phase 1: per-head max over incoming edges
    float4 m = make_float4(-1e30f, -1e30f, -1e30f, -1e30f);
    for (int j = beg + lane; j < end; j += 64) {
        float4 a = aex4[csr_eid[j]];
        m.x = fmaxf(m.x, a.x); m.y = fmaxf(m.y, a.y);
        m.z = fmaxf(m.z, a.z); m.w = fmaxf(m.w, a.w);
    }
#pragma unroll
    for (int off = 32; off; off >>= 1) {
        m.x = fmaxf(m.x, __shfl_xor(m.x, off));
        m.y = fmaxf(m.y, __shfl_xor(m.y, off));
        m.z = fmaxf(m.z, __shfl_xor(m.z, off));
        m.w = fmaxf(m.w, __shfl_xor(m.w, off));
    }

    // phase 2: per-head sum of exp
    float4 ssum = make_float4(0.f, 0.f, 0.f, 0.f);
    for (int j = beg + lane; j < end; j += 64) {
        float4 a = aex4[csr_eid[j]];
        ssum.x += __expf(a.x - m.x); ssum.y += __expf(a.y - m.y);
        ssum.z += __expf(a.z - m.z); ssum.w += __expf(a.w - m.w);
    }
#pragma unroll
    for (int off = 32; off; off >>= 1) {
        ssum.x += __shfl_xor(ssum.x, off);
        ssum.y += __shfl_xor(ssum.y, off);
        ssum.z += __shfl_xor(ssum.z, off);
        ssum.w += __shfl_xor(ssum.w, off);
    }

    int h = lane >> 4;  // channels 2*lane..2*lane+1 all belong to head h
    float mh   = (h == 0) ? m.x : (h == 1) ? m.y : (h == 2) ? m.z : m.w;
    float dh   = (h == 0) ? ssum.x : (h == 1) ? ssum.y : (h == 2) ? ssum.z : ssum.w;
    float invh = 1.0f / dh;

    // phase 3: accumulate alpha * xp[src] (2 channels per lane, in registers)
    const float2* xp2 = (const float2*)xp;
    float2 acc = make_float2(0.f, 0.f);
    for (int j = beg; j < end; j++) {
        int e = csr_eid[j];
        int s = csr_src[j];
        float a  = aex[e * 4 + h];
        float al = __expf(a - mh) * invh;
        float2 v = xp2[(size_t)s * 64 + lane];
        acc.x += al * v.x;
        acc.y += al * v.y;
    }
    ((float2*)out)[(size_t)gw * 64 + lane] = acc;
}

// ---------------------------------------------------------------------------
// BatchNorm statistics + finalize + fused update (BN affine, relu, residual)
// ---------------------------------------------------------------------------
__launch_bounds__(256)
__global__ void bnstats_kernel(const float* __restrict__ h, float* __restrict__ bnsum,
                               float* __restrict__ bnsum2) {
    __shared__ float ls[256], ls2[256];
    int t = threadIdx.x;
    int c = t & 127, half = t >> 7;
    int r0 = blockIdx.x * 128;
    float s = 0.f, s2 = 0.f;
    int rend = min(r0 + 128, N_NODES);
    for (int r = r0 + half; r < rend; r += 2) {
        float v = h[(size_t)r * 128 + c];
        s += v; s2 += v * v;
    }
    ls[t] = s; ls2[t] = s2;
    __syncthreads();
    if (half == 0) {
        s += ls[t + 128]; s2 += ls2[t + 128];
        atomicAdd(&bnsum[c], s);
        atomicAdd(&bnsum2[c], s2);
    }
}

__global__ void bnfinal_kernel(const float* __restrict__ bnsum, const float* __restrict__ bnsum2,
                               const float* __restrict__ gamma, const float* __restrict__ beta,
                               float* __restrict__ scale, float* __restrict__ shift) {
    int c = threadIdx.x;
    if (c >= 128) return;
    float mu = bnsum[c] / (float)N_NODES;
    float var = bnsum2[c] / (float)N_NODES - mu * mu;
    float inv = rsqrtf(var + BN_EPS);
    float g = gamma[c] * inv;
    scale[c] = g;
    shift[c] = beta[c] - mu * g;
}

__launch_bounds__(256)
__global__ void update_kernel(const float* __restrict__ outb, const float* __restrict__ scale,
                              const float* __restrict__ shift, const float* __restrict__ hA,
                              float* __restrict__ dst, int add_res) {
    int i = blockIdx.x * blockDim.x + threadIdx.x;
    if (i >= N_NODES * 32) return;
    int c4 = i & 31;
    float4 o  = ((const float4*)outb)[i];
    float4 sc = ((const float4*)scale)[c4];
    float4 sh = ((const float4*)shift)[c4];
    float4 v;
    v.x = fmaxf(o.x * sc.x + sh.x, 0.f);
    v.y = fmaxf(o.y * sc.y + sh.y, 0.f);
    v.z = fmaxf(o.z * sc.z + sh.z, 0.f);
    v.w = fmaxf(o.w * sc.w + sh.w, 0.f);
    if (add_res) {
        float4 hh = ((const float4*)hA)[i];
        v.x += hh.x; v.y += hh.y; v.z += hh.z; v.w += hh.w;
    }
    ((float4*)dst)[i] = v;
}

// ---------------------------------------------------------------------------
extern "C" void kernel_launch(void* const* d_in, const int* in_sizes, int n_in,
                              void* d_out, int out_size, void* d_ws, size_t ws_size,
                              hipStream_t stream) {
    const float* x          = (const float*)d_in[0];
    const int*   edge_index = (const int*)d_in[1];
    const float* edge_attr  = (const float*)d_in[2];
    const float* Wp         = (const float*)d_in[3];
    const float* bp         = (const float*)d_in[4];
    const float* W          = (const float*)d_in[5];
    const float* We         = (const float*)d_in[6];
    const float* att_src    = (const float*)d_in[7];
    const float* att_dst    = (const float*)d_in[8];
    const float* att_edge   = (const float*)d_in[9];
    // d_in[10] bias: absorbed exactly by training-mode BN -> skipped
    const float* gamma      = (const float*)d_in[11];
    const float* beta       = (const float*)d_in[12];
    float* outp = (float*)d_out;

    const int* ei_src = edge_index;
    const int* ei_dst = edge_index + N_EDGES;

    char* p = (char*)d_ws;
    auto alloc = [&](size_t nbytes) {
        char* r = p;
        p += (nbytes + 255) & ~(size_t)255;
        return r;
    };
    float* hA      = (float*)alloc((size_t)N_NODES * 128 * 4);
    float* xp      = (float*)alloc((size_t)N_NODES * 128 * 4);
    float* outb    = (float*)alloc((size_t)N_NODES * 128 * 4);
    float* aex     = (float*)alloc((size_t)N_ETOT * 4 * 4);
    float* asrc    = (float*)alloc((size_t)N_NODES * 4 * 4);
    float* adst    = (float*)alloc((size_t)N_NODES * 4 * 4);
    float* bnsum   = (float*)alloc(512 * 4);   // bnsum|bnsum2|scale|shift
    float* bnsum2  = bnsum + 128;
    float* bnscale = bnsum + 256;
    float* bnshift = bnsum + 384;
    float* easum   = (float*)alloc(16 * 4);
    float* wea_all = (float*)alloc((LAYERS * 48 + 16) * 4);
    float* aloop   = wea_all + LAYERS * 48;
    int* hist      = (int*)alloc((size_t)N_NODES * 4);
    int* rowp      = (int*)alloc(((size_t)N_NODES + 1) * 4);
    int* cursor    = (int*)alloc((size_t)N_NODES * 4);
    int* csr_eid   = (int*)alloc((size_t)N_ETOT * 4);
    int* csr_src   = (int*)alloc((size_t)N_ETOT * 4);

    const int EB = (N_ETOT + 255) / 256;
    const int NB = (N_NODES + 255) / 256;

    // ---- CSR build (graph fixed across layers) ----
    hipMemsetAsync(hist, 0, (size_t)N_NODES * 4, stream);
    hipMemsetAsync(easum, 0, 16 * 4, stream);
    hist_kernel<<<EB, 256, 0, stream>>>(ei_dst, hist);
    scan_kernel<<<1, 1024, 0, stream>>>(hist, rowp, cursor);
    scatter_kernel<<<EB, 256, 0, stream>>>(ei_src, ei_dst, cursor, csr_eid, csr_src);

    // ---- edge-attr mean + folded edge-attention matrices (all layers) ----
    eamean_kernel<<<256, 256, 0, stream>>>(edge_attr, easum);
    prep_kernel<<<1, 256, 0, stream>>>(easum, We, att_edge, wea_all, aloop);

    // ---- initial projection ----
    gemm_kernel<64><<<(N_NODES + 63) / 64, 256, 0, stream>>>(x, Wp, bp, hA, N_NODES, 1);

    for (int l = 0; l < LAYERS; l++) {
        gemm_kernel<128><<<(N_NODES + 63) / 64, 256, 0, stream>>>(
            hA, W + (size_t)l * 128 * 128, nullptr, xp, N_NODES, 0);
        attdot_kernel<<<NB, 256, 0, stream>>>(xp, att_src + l * 128, att_dst + l * 128,
                                              asrc, adst);
        edge_kernel<<<EB, 256, 0, stream>>>(ei_src, ei_dst, edge_attr, asrc, adst,
                                            wea_all + l * 48, aloop + l * 4, aex);
        node_kernel<<<(N_NODES + 3) / 4, 256, 0, stream>>>(aex, rowp, csr_eid, csr_src,
                                                           xp, outb);
        hipMemsetAsync(bnsum, 0, 256 * 4, stream);
        bnstats_kernel<<<(N_NODES + 127) / 128, 256, 0, stream>>>(outb, bnsum, bnsum2);
        bnfinal_kernel<<<1, 128, 0, stream>>>(bnsum, bnsum2, gamma + l * 128,
                                              beta + l * 128, bnscale, bnshift);
        float* dst = (l == LAYERS - 1) ? outp : hA;
        update_kernel<<<(N_NODES * 32 + 255) / 256, 256, 0, stream>>>(
            outb, bnscale, bnshift, hA, dst, (l > 0) ? 1 : 0);
    }
}

// Round 2
// 1189.731 us; speedup vs baseline: 1.0303x; 1.0303x over previous
//
#include <hip/hip_runtime.h>

// Problem constants (match reference setup_inputs)
constexpr int N_NODES = 50000;
constexpr int N_EDGES = 800000;
constexpr int N_ETOT  = N_EDGES + N_NODES;   // with self loops
constexpr int HID     = 128;
constexpr int HEADS   = 4;
constexpr int ED      = 12;
constexpr int LAYERS  = 4;
constexpr float BN_EPS = 1e-5f;
constexpr int SCAN_BLK = (N_NODES + 255) / 256;   // 196

// ---------------------------------------------------------------------------
// CSR build: histogram of dst, multi-block scan, scatter (stores epos[e])
// ---------------------------------------------------------------------------
__global__ void hist_kernel(const int* __restrict__ dst, int* __restrict__ hist) {
    int e = blockIdx.x * blockDim.x + threadIdx.x;
    if (e >= N_ETOT) return;
    int d = (e < N_EDGES) ? dst[e] : (e - N_EDGES);
    atomicAdd(&hist[d], 1);
}

// per-block sums of hist (256 elems per block)
__global__ void blocksum_kernel(const int* __restrict__ hist, int* __restrict__ bsum) {
    __shared__ int sd[256];
    int t = threadIdx.x;
    int n = blockIdx.x * 256 + t;
    sd[t] = (n < N_NODES) ? hist[n] : 0;
    __syncthreads();
#pragma unroll
    for (int off = 128; off; off >>= 1) {
        if (t < off) sd[t] += sd[t + off];
        __syncthreads();
    }
    if (t == 0) bsum[blockIdx.x] = sd[0];
}

// single small block: exclusive scan of the 196 block sums
__global__ void bscan_kernel(const int* __restrict__ bsum, int* __restrict__ boff,
                             int* __restrict__ rowp) {
    __shared__ int sd[256];
    int t = threadIdx.x;
    int v = (t < SCAN_BLK) ? bsum[t] : 0;
    sd[t] = v;
    __syncthreads();
#pragma unroll
    for (int off = 1; off < 256; off <<= 1) {
        int u = (t >= off) ? sd[t - off] : 0;
        __syncthreads();
        sd[t] += u;
        __syncthreads();
    }
    if (t < SCAN_BLK) boff[t] = sd[t] - v;   // exclusive
    if (t == 255) rowp[N_NODES] = sd[255];   // total = N_ETOT
}

// per-block exclusive scan + block offset -> rowp, cursor
__global__ void rowp_kernel(const int* __restrict__ hist, const int* __restrict__ boff,
                            int* __restrict__ rowp, int* __restrict__ cursor) {
    __shared__ int sd[256];
    int t = threadIdx.x;
    int n = blockIdx.x * 256 + t;
    int v = (n < N_NODES) ? hist[n] : 0;
    sd[t] = v;
    __syncthreads();
#pragma unroll
    for (int off = 1; off < 256; off <<= 1) {
        int u = (t >= off) ? sd[t - off] : 0;
        __syncthreads();
        sd[t] += u;
        __syncthreads();
    }
    if (n < N_NODES) {
        int excl = sd[t] - v + boff[blockIdx.x];
        rowp[n] = excl;
        cursor[n] = excl;
    }
}

__global__ void scatter_kernel(const int* __restrict__ src, const int* __restrict__ dst,
                               int* __restrict__ cursor, int* __restrict__ epos,
                               int* __restrict__ csr_src) {
    int e = blockIdx.x * blockDim.x + threadIdx.x;
    if (e >= N_ETOT) return;
    int s, d;
    if (e < N_EDGES) { s = src[e]; d = dst[e]; }
    else             { s = d = e - N_EDGES; }
    int pos = atomicAdd(&cursor[d], 1);
    epos[e] = pos;
    csr_src[pos] = s;
}

// ---------------------------------------------------------------------------
// edge_attr mean (over real edges) -> easum[12]
// ---------------------------------------------------------------------------
__launch_bounds__(256)
__global__ void eamean_kernel(const float* __restrict__ ea, float* __restrict__ easum) {
    __shared__ float ls[12];
    int t = threadIdx.x;
    if (t < 12) ls[t] = 0.f;
    __syncthreads();
    float loc[12];
#pragma unroll
    for (int d = 0; d < 12; d++) loc[d] = 0.f;
    int stride = gridDim.x * 256;
    for (int e = blockIdx.x * 256 + t; e < N_EDGES; e += stride) {
        const float* er = ea + (size_t)e * ED;
#pragma unroll
        for (int d = 0; d < 12; d++) loc[d] += er[d];
    }
#pragma unroll
    for (int d = 0; d < 12; d++) atomicAdd(&ls[d], loc[d]);
    __syncthreads();
    if (t < 12) atomicAdd(&easum[t], ls[t]);
}

// Precompute per-layer Wea[12][4] (= We folded with att_edge) and self-loop
// attention contribution aloop[4] = ea_mean @ Wea.
__global__ void prep_kernel(const float* __restrict__ easum, const float* __restrict__ We,
                            const float* __restrict__ att_edge, float* __restrict__ wea_all,
                            float* __restrict__ aloop) {
    __shared__ float em[12];
    __shared__ float weash[LAYERS * ED * HEADS];  // 192
    int t = threadIdx.x;
    if (t < 12) em[t] = easum[t] / (float)N_EDGES;
    if (t < LAYERS * ED * HEADS) {
        int l = t / (ED * HEADS);
        int r = t % (ED * HEADS);
        int d = r / HEADS;
        int h = r % HEADS;
        float sum = 0.f;
#pragma unroll
        for (int c = 0; c < 32; c++)
            sum += We[((size_t)(l * ED + d)) * HID + h * 32 + c] *
                   att_edge[(l * HEADS + h) * 32 + c];
        wea_all[t] = sum;
        weash[t] = sum;
    }
    __syncthreads();
    if (t < LAYERS * HEADS) {
        int l = t / HEADS, h = t % HEADS;
        float s = 0.f;
#pragma unroll
        for (int d = 0; d < 12; d++) s += em[d] * weash[l * ED * HEADS + d * HEADS + h];
        aloop[t] = s;
    }
}

// ---------------------------------------------------------------------------
// GEMM: C[M,128] = A[M,K] @ B[K,128] (+bias, relu optional). B staged in LDS.
// Block: 256 threads -> 64 rows x 128 cols; thread: 4 rows x 8 cols.
// ---------------------------------------------------------------------------
template <int K>
__launch_bounds__(256)
__global__ void gemm_kernel(const float* __restrict__ A, const float* __restrict__ B,
                            const float* __restrict__ bias, float* __restrict__ C,
                            int M, int fuse_relu) {
    __shared__ float Bs[K * 128];
    int t = threadIdx.x;
    const float4* B4 = (const float4*)B;
    float4* Bs4 = (float4*)Bs;
#pragma unroll
    for (int i = t; i < K * 32; i += 256) Bs4[i] = B4[i];
    __syncthreads();

    int c0 = (t & 15) * 8;
    int r0 = (t >> 4) * 4;
    int rbase = blockIdx.x * 64 + r0;

    float acc[4][8];
#pragma unroll
    for (int j = 0; j < 4; j++)
#pragma unroll
        for (int c = 0; c < 8; c++) acc[j][c] = 0.f;

    const float4* A4 = (const float4*)A;
    int rg[4];
#pragma unroll
    for (int j = 0; j < 4; j++) rg[j] = min(rbase + j, M - 1);

    for (int kk = 0; kk < K; kk += 4) {
        float4 av[4];
#pragma unroll
        for (int j = 0; j < 4; j++) av[j] = A4[(size_t)rg[j] * (K / 4) + (kk >> 2)];
        float a_arr[4][4];
#pragma unroll
        for (int j = 0; j < 4; j++) {
            a_arr[j][0] = av[j].x; a_arr[j][1] = av[j].y;
            a_arr[j][2] = av[j].z; a_arr[j][3] = av[j].w;
        }
#pragma unroll
        for (int jj = 0; jj < 4; jj++) {
            float4 b0 = Bs4[(kk + jj) * 32 + (c0 >> 2)];
            float4 b1 = Bs4[(kk + jj) * 32 + (c0 >> 2) + 1];
#pragma unroll
            for (int j = 0; j < 4; j++) {
                float a = a_arr[j][jj];
                acc[j][0] += a * b0.x; acc[j][1] += a * b0.y;
                acc[j][2] += a * b0.z; acc[j][3] += a * b0.w;
                acc[j][4] += a * b1.x; acc[j][5] += a * b1.y;
                acc[j][6] += a * b1.z; acc[j][7] += a * b1.w;
            }
        }
    }

#pragma unroll
    for (int j = 0; j < 4; j++) {
        int r = rbase + j;
        if (r < M) {
            float4 o0, o1;
            o0.x = acc[j][0]; o0.y = acc[j][1]; o0.z = acc[j][2]; o0.w = acc[j][3];
            o1.x = acc[j][4]; o1.y = acc[j][5]; o1.z = acc[j][6]; o1.w = acc[j][7];
            if (bias) {
                o0.x += bias[c0 + 0]; o0.y += bias[c0 + 1];
                o0.z += bias[c0 + 2]; o0.w += bias[c0 + 3];
                o1.x += bias[c0 + 4]; o1.y += bias[c0 + 5];
                o1.z += bias[c0 + 6]; o1.w += bias[c0 + 7];
            }
            if (fuse_relu) {
                o0.x = fmaxf(o0.x, 0.f); o0.y = fmaxf(o0.y, 0.f);
                o0.z = fmaxf(o0.z, 0.f); o0.w = fmaxf(o0.w, 0.f);
                o1.x = fmaxf(o1.x, 0.f); o1.y = fmaxf(o1.y, 0.f);
                o1.z = fmaxf(o1.z, 0.f); o1.w = fmaxf(o1.w, 0.f);
            }
            ((float4*)(C + (size_t)r * 128 + c0))[0] = o0;
            ((float4*)(C + (size_t)r * 128 + c0 + 4))[0] = o1;
        }
    }
}

// ---------------------------------------------------------------------------
// Per-node attention dot products: a_src[n,h], a_dst[n,h]
// ---------------------------------------------------------------------------
__global__ void attdot_kernel(const float* __restrict__ xp, const float* __restrict__ att_s,
                              const float* __restrict__ att_d, float* __restrict__ asrc,
                              float* __restrict__ adst) {
    int n = blockIdx.x * blockDim.x + threadIdx.x;
    if (n >= N_NODES) return;
    const float4* x4 = (const float4*)(xp + (size_t)n * 128);
    const float4* s4 = (const float4*)att_s;
    const float4* d4 = (const float4*)att_d;
    float rs[4], rd[4];
#pragma unroll
    for (int h = 0; h < 4; h++) {
        float ss = 0.f, dd = 0.f;
#pragma unroll
        for (int q = 0; q < 8; q++) {
            float4 v = x4[h * 8 + q];
            float4 a = s4[h * 8 + q];
            float4 b = d4[h * 8 + q];
            ss += v.x * a.x + v.y * a.y + v.z * a.z + v.w * a.w;
            dd += v.x * b.x + v.y * b.y + v.z * b.z + v.w * b.w;
        }
        rs[h] = ss; rd[h] = dd;
    }
    ((float4*)asrc)[n] = make_float4(rs[0], rs[1], rs[2], rs[3]);
    ((float4*)adst)[n] = make_float4(rd[0], rd[1], rd[2], rd[3]);
}

// ---------------------------------------------------------------------------
// Per-edge: ex = exp(leakyrelu(a_src+a_dst+a_edge)), scattered to CSR slot.
// No max-subtraction: logits are O(1) by construction (BN-bounded activations
// x 0.1-scale weights); clamp at 60 for safety. Softmax is shift-invariant so
// unnormalized exp + divide in node_kernel is exact.
// ---------------------------------------------------------------------------
__launch_bounds__(256)
__global__ void edge_kernel(const int* __restrict__ src, const int* __restrict__ dst,
                            const float* __restrict__ ea, const float* __restrict__ asrc,
                            const float* __restrict__ adst, const float* __restrict__ wea,
                            const float* __restrict__ aloop, const int* __restrict__ epos,
                            float* __restrict__ exs) {
    int e = blockIdx.x * blockDim.x + threadIdx.x;
    if (e >= N_ETOT) return;
    int s, d;
    float ae0, ae1, ae2, ae3;
    if (e < N_EDGES) {
        s = src[e]; d = dst[e];
        ae0 = ae1 = ae2 = ae3 = 0.f;
        const float* er = ea + (size_t)e * ED;
#pragma unroll
        for (int dd = 0; dd < 12; dd++) {
            float v = er[dd];
            ae0 += v * wea[dd * 4 + 0];
            ae1 += v * wea[dd * 4 + 1];
            ae2 += v * wea[dd * 4 + 2];
            ae3 += v * wea[dd * 4 + 3];
        }
    } else {
        s = d = e - N_EDGES;
        ae0 = aloop[0]; ae1 = aloop[1]; ae2 = aloop[2]; ae3 = aloop[3];
    }
    float4 as = ((const float4*)asrc)[s];
    float4 ad = ((const float4*)adst)[d];
    float a0 = as.x + ad.x + ae0;
    float a1 = as.y + ad.y + ae1;
    float a2 = as.z + ad.z + ae2;
    float a3 = as.w + ad.w + ae3;
    a0 = (a0 > 0.f) ? a0 : 0.2f * a0;
    a1 = (a1 > 0.f) ? a1 : 0.2f * a1;
    a2 = (a2 > 0.f) ? a2 : 0.2f * a2;
    a3 = (a3 > 0.f) ? a3 : 0.2f * a3;
    float4 ex;
    ex.x = __expf(fminf(a0, 60.f));
    ex.y = __expf(fminf(a1, 60.f));
    ex.z = __expf(fminf(a2, 60.f));
    ex.w = __expf(fminf(a3, 60.f));
    ((float4*)exs)[epos[e]] = ex;
}

// ---------------------------------------------------------------------------
// Single-pass aggregation: one wave per destination node; lane owns channels
// 2*lane, 2*lane+1 (head h = lane>>4). out = (sum ex*xp[src]) / (sum ex).
// Per-edge reads are wave-uniform (scalar loads); only xp row gather is random.
// ---------------------------------------------------------------------------
__launch_bounds__(256)
__global__ void node_kernel(const float* __restrict__ exs, const int* __restrict__ rowp,
                            const int* __restrict__ csr_src, const float* __restrict__ xp,
                            float* __restrict__ out) {
    int gw = (blockIdx.x * blockDim.x + threadIdx.x) >> 6;
    int lane = threadIdx.x & 63;
    if (gw >= N_NODES) return;
    int beg = rowp[gw], end = rowp[gw + 1];
    int h = lane >> 4;
    const float4* exs4 = (const float4*)exs;
    const float2* xp2 = (const float2*)xp;

    float2 acc = make_float2(0.f, 0.f);
    float den = 0.f;
    for (int j = beg; j < end; j++) {
        float4 ex4 = exs4[j];
        int s = csr_src[j];
        float exh = (h == 0) ? ex4.x : (h == 1) ? ex4.y : (h == 2) ? ex4.z : ex4.w;
        float2 v = xp2[(size_t)s * 64 + lane];
        acc.x += exh * v.x;
        acc.y += exh * v.y;
        den += exh;
    }
    float inv = 1.0f / den;   // deg >= 1 (self loop)
    ((float2*)out)[(size_t)gw * 64 + lane] = make_float2(acc.x * inv, acc.y * inv);
}

// ---------------------------------------------------------------------------
// BatchNorm statistics + finalize + fused update (BN affine, relu, residual)
// ---------------------------------------------------------------------------
__launch_bounds__(256)
__global__ void bnstats_kernel(const float* __restrict__ h, float* __restrict__ bnsum,
                               float* __restrict__ bnsum2) {
    __shared__ float ls[256], ls2[256];
    int t = threadIdx.x;
    int c = t & 127, half = t >> 7;
    int r0 = blockIdx.x * 128;
    float s = 0.f, s2 = 0.f;
    int rend = min(r0 + 128, N_NODES);
    for (int r = r0 + half; r < rend; r += 2) {
        float v = h[(size_t)r * 128 + c];
        s += v; s2 += v * v;
    }
    ls[t] = s; ls2[t] = s2;
    __syncthreads();
    if (half == 0) {
        s += ls[t + 128]; s2 += ls2[t + 128];
        atomicAdd(&bnsum[c], s);
        atomicAdd(&bnsum2[c], s2);
    }
}

__global__ void bnfinal_kernel(const float* __restrict__ bnsum, const float* __restrict__ bnsum2,
                               const float* __restrict__ gamma, const float* __restrict__ beta,
                               float* __restrict__ scale, float* __restrict__ shift) {
    int c = threadIdx.x;
    if (c >= 128) return;
    float mu = bnsum[c] / (float)N_NODES;
    float var = bnsum2[c] / (float)N_NODES - mu * mu;
    float inv = rsqrtf(var + BN_EPS);
    float g = gamma[c] * inv;
    scale[c] = g;
    shift[c] = beta[c] - mu * g;
}

__launch_bounds__(256)
__global__ void update_kernel(const float* __restrict__ outb, const float* __restrict__ scale,
                              const float* __restrict__ shift, const float* __restrict__ hA,
                              float* __restrict__ dst, int add_res) {
    int i = blockIdx.x * blockDim.x + threadIdx.x;
    if (i >= N_NODES * 32) return;
    int c4 = i & 31;
    float4 o  = ((const float4*)outb)[i];
    float4 sc = ((const float4*)scale)[c4];
    float4 sh = ((const float4*)shift)[c4];
    float4 v;
    v.x = fmaxf(o.x * sc.x + sh.x, 0.f);
    v.y = fmaxf(o.y * sc.y + sh.y, 0.f);
    v.z = fmaxf(o.z * sc.z + sh.z, 0.f);
    v.w = fmaxf(o.w * sc.w + sh.w, 0.f);
    if (add_res) {
        float4 hh = ((const float4*)hA)[i];
        v.x += hh.x; v.y += hh.y; v.z += hh.z; v.w += hh.w;
    }
    ((float4*)dst)[i] = v;
}

// ---------------------------------------------------------------------------
extern "C" void kernel_launch(void* const* d_in, const int* in_sizes, int n_in,
                              void* d_out, int out_size, void* d_ws, size_t ws_size,
                              hipStream_t stream) {
    const float* x          = (const float*)d_in[0];
    const int*   edge_index = (const int*)d_in[1];
    const float* edge_attr  = (const float*)d_in[2];
    const float* Wp         = (const float*)d_in[3];
    const float* bp         = (const float*)d_in[4];
    const float* W          = (const float*)d_in[5];
    const float* We         = (const float*)d_in[6];
    const float* att_src    = (const float*)d_in[7];
    const float* att_dst    = (const float*)d_in[8];
    const float* att_edge   = (const float*)d_in[9];
    // d_in[10] bias: absorbed exactly by training-mode BN -> skipped
    const float* gamma      = (const float*)d_in[11];
    const float* beta       = (const float*)d_in[12];
    float* outp = (float*)d_out;

    const int* ei_src = edge_index;
    const int* ei_dst = edge_index + N_EDGES;

    char* p = (char*)d_ws;
    auto alloc = [&](size_t nbytes) {
        char* r = p;
        p += (nbytes + 255) & ~(size_t)255;
        return r;
    };
    float* hA      = (float*)alloc((size_t)N_NODES * 128 * 4);
    float* xp      = (float*)alloc((size_t)N_NODES * 128 * 4);
    float* outb    = (float*)alloc((size_t)N_NODES * 128 * 4);
    float* exs     = (float*)alloc((size_t)N_ETOT * 4 * 4);
    float* asrc    = (float*)alloc((size_t)N_NODES * 4 * 4);
    float* adst    = (float*)alloc((size_t)N_NODES * 4 * 4);
    float* bnsum   = (float*)alloc(512 * 4);   // bnsum|bnsum2|scale|shift
    float* bnsum2  = bnsum + 128;
    float* bnscale = bnsum + 256;
    float* bnshift = bnsum + 384;
    float* easum   = (float*)alloc(16 * 4);
    float* wea_all = (float*)alloc((LAYERS * 48 + 16) * 4);
    float* aloop   = wea_all + LAYERS * 48;
    int* hist      = (int*)alloc((size_t)N_NODES * 4);
    int* rowp      = (int*)alloc(((size_t)N_NODES + 1) * 4);
    int* cursor    = (int*)alloc((size_t)N_NODES * 4);
    int* epos      = (int*)alloc((size_t)N_ETOT * 4);
    int* csr_src   = (int*)alloc((size_t)N_ETOT * 4);
    int* bsum      = (int*)alloc(256 * 4);
    int* boff      = (int*)alloc(256 * 4);

    const int EB = (N_ETOT + 255) / 256;
    const int NB = (N_NODES + 255) / 256;

    // ---- CSR build (graph fixed across layers) ----
    hipMemsetAsync(hist, 0, (size_t)N_NODES * 4, stream);
    hipMemsetAsync(easum, 0, 16 * 4, stream);
    hist_kernel<<<EB, 256, 0, stream>>>(ei_dst, hist);
    blocksum_kernel<<<SCAN_BLK, 256, 0, stream>>>(hist, bsum);
    bscan_kernel<<<1, 256, 0, stream>>>(bsum, boff, rowp);
    rowp_kernel<<<SCAN_BLK, 256, 0, stream>>>(hist, boff, rowp, cursor);
    scatter_kernel<<<EB, 256, 0, stream>>>(ei_src, ei_dst, cursor, epos, csr_src);

    // ---- edge-attr mean + folded edge-attention matrices (all layers) ----
    eamean_kernel<<<256, 256, 0, stream>>>(edge_attr, easum);
    prep_kernel<<<1, 256, 0, stream>>>(easum, We, att_edge, wea_all, aloop);

    // ---- initial projection ----
    gemm_kernel<64><<<(N_NODES + 63) / 64, 256, 0, stream>>>(x, Wp, bp, hA, N_NODES, 1);

    for (int l = 0; l < LAYERS; l++) {
        gemm_kernel<128><<<(N_NODES + 63) / 64, 256, 0, stream>>>(
            hA, W + (size_t)l * 128 * 128, nullptr, xp, N_NODES, 0);
        attdot_kernel<<<NB, 256, 0, stream>>>(xp, att_src + l * 128, att_dst + l * 128,
                                              asrc, adst);
        edge_kernel<<<EB, 256, 0, stream>>>(ei_src, ei_dst, edge_attr, asrc, adst,
                                            wea_all + l * 48, aloop + l * 4, epos, exs);
        node_kernel<<<(N_NODES + 3) / 4, 256, 0, stream>>>(exs, rowp, csr_src, xp, outb);
        hipMemsetAsync(bnsum, 0, 256 * 4, stream);
        bnstats_kernel<<<(N_NODES + 127) / 128, 256, 0, stream>>>(outb, bnsum, bnsum2);
        bnfinal_kernel<<<1, 128, 0, stream>>>(bnsum, bnsum2, gamma + l * 128,
                                              beta + l * 128, bnscale, bnshift);
        float* dst = (l == LAYERS - 1) ? outp : hA;
        update_kernel<<<(N_NODES * 32 + 255) / 256, 256, 0, stream>>>(
            outb, bnscale, bnshift, hA, dst, (l > 0) ? 1 : 0);
    }
}

// Round 4
// 945.752 us; speedup vs baseline: 1.2961x; 1.2580x over previous
//
#include <hip/hip_runtime.h>

// Problem constants (match reference setup_inputs)
constexpr int N_NODES = 50000;
constexpr int N_EDGES = 800000;
constexpr int N_ETOT  = N_EDGES + N_NODES;   // with self loops
constexpr int HID     = 128;
constexpr int HEADS   = 4;
constexpr int ED      = 12;
constexpr int LAYERS  = 4;
constexpr float BN_EPS = 1e-5f;
constexpr int SCAN_BLK = (N_NODES + 255) / 256;   // 196

__device__ inline unsigned bf16pair(float a, float b) {
    unsigned ua = __float_as_uint(a), ub = __float_as_uint(b);
    ua = (ua + 0x7FFFu + ((ua >> 16) & 1u)) >> 16;
    ub = (ub + 0x7FFFu + ((ub >> 16) & 1u)) >> 16;
    return ua | (ub << 16);
}

// ---------------------------------------------------------------------------
// CSR build: histogram of dst, multi-block scan, scatter (stores epos[e])
// ---------------------------------------------------------------------------
__global__ void hist_kernel(const int* __restrict__ dst, int* __restrict__ hist) {
    int e = blockIdx.x * blockDim.x + threadIdx.x;
    if (e >= N_ETOT) return;
    int d = (e < N_EDGES) ? dst[e] : (e - N_EDGES);
    atomicAdd(&hist[d], 1);
}

__global__ void blocksum_kernel(const int* __restrict__ hist, int* __restrict__ bsum) {
    __shared__ int sd[256];
    int t = threadIdx.x;
    int n = blockIdx.x * 256 + t;
    sd[t] = (n < N_NODES) ? hist[n] : 0;
    __syncthreads();
#pragma unroll
    for (int off = 128; off; off >>= 1) {
        if (t < off) sd[t] += sd[t + off];
        __syncthreads();
    }
    if (t == 0) bsum[blockIdx.x] = sd[0];
}

__global__ void bscan_kernel(const int* __restrict__ bsum, int* __restrict__ boff,
                             int* __restrict__ rowp) {
    __shared__ int sd[256];
    int t = threadIdx.x;
    int v = (t < SCAN_BLK) ? bsum[t] : 0;
    sd[t] = v;
    __syncthreads();
#pragma unroll
    for (int off = 1; off < 256; off <<= 1) {
        int u = (t >= off) ? sd[t - off] : 0;
        __syncthreads();
        sd[t] += u;
        __syncthreads();
    }
    if (t < SCAN_BLK) boff[t] = sd[t] - v;
    if (t == 255) rowp[N_NODES] = sd[255];
}

__global__ void rowp_kernel(const int* __restrict__ hist, const int* __restrict__ boff,
                            int* __restrict__ rowp, int* __restrict__ cursor) {
    __shared__ int sd[256];
    int t = threadIdx.x;
    int n = blockIdx.x * 256 + t;
    int v = (n < N_NODES) ? hist[n] : 0;
    sd[t] = v;
    __syncthreads();
#pragma unroll
    for (int off = 1; off < 256; off <<= 1) {
        int u = (t >= off) ? sd[t - off] : 0;
        __syncthreads();
        sd[t] += u;
        __syncthreads();
    }
    if (n < N_NODES) {
        int excl = sd[t] - v + boff[blockIdx.x];
        rowp[n] = excl;
        cursor[n] = excl;
    }
}

__global__ void scatter_kernel(const int* __restrict__ src, const int* __restrict__ dst,
                               int* __restrict__ cursor, int* __restrict__ epos,
                               int* __restrict__ csr_src) {
    int e = blockIdx.x * blockDim.x + threadIdx.x;
    if (e >= N_ETOT) return;
    int s, d;
    if (e < N_EDGES) { s = src[e]; d = dst[e]; }
    else             { s = d = e - N_EDGES; }
    int pos = atomicAdd(&cursor[d], 1);
    epos[e] = pos;
    csr_src[pos] = s;
}

// ---------------------------------------------------------------------------
// edge_attr mean (over real edges) -> easum[12]
// ---------------------------------------------------------------------------
__launch_bounds__(256)
__global__ void eamean_kernel(const float* __restrict__ ea, float* __restrict__ easum) {
    __shared__ float ls[12];
    int t = threadIdx.x;
    if (t < 12) ls[t] = 0.f;
    __syncthreads();
    float loc[12];
#pragma unroll
    for (int d = 0; d < 12; d++) loc[d] = 0.f;
    int stride = gridDim.x * 256;
    for (int e = blockIdx.x * 256 + t; e < N_EDGES; e += stride) {
        const float* er = ea + (size_t)e * ED;
#pragma unroll
        for (int d = 0; d < 12; d++) loc[d] += er[d];
    }
#pragma unroll
    for (int d = 0; d < 12; d++) atomicAdd(&ls[d], loc[d]);
    __syncthreads();
    if (t < 12) atomicAdd(&easum[t], ls[t]);
}

__global__ void prep_kernel(const float* __restrict__ easum, const float* __restrict__ We,
                            const float* __restrict__ att_edge, float* __restrict__ wea_all,
                            float* __restrict__ aloop) {
    __shared__ float em[12];
    __shared__ float weash[LAYERS * ED * HEADS];
    int t = threadIdx.x;
    if (t < 12) em[t] = easum[t] / (float)N_EDGES;
    if (t < LAYERS * ED * HEADS) {
        int l = t / (ED * HEADS);
        int r = t % (ED * HEADS);
        int d = r / HEADS;
        int h = r % HEADS;
        float sum = 0.f;
#pragma unroll
        for (int c = 0; c < 32; c++)
            sum += We[((size_t)(l * ED + d)) * HID + h * 32 + c] *
                   att_edge[(l * HEADS + h) * 32 + c];
        wea_all[t] = sum;
        weash[t] = sum;
    }
    __syncthreads();
    if (t < LAYERS * HEADS) {
        int l = t / HEADS, h = t % HEADS;
        float s = 0.f;
#pragma unroll
        for (int d = 0; d < 12; d++) s += em[d] * weash[l * ED * HEADS + d * HEADS + h];
        aloop[t] = s;
    }
}

// ---------------------------------------------------------------------------
// GEMM: [M,K]@[K,128]. FUSE=0: f32 out + bias + relu (initial projection).
// FUSE=1: bf16 out (xpb, 64 dwords/row) + fused attention dots asrc/adst.
// Block: 256 threads -> 64 rows x 128 cols; thread: 4 rows x 8 cols.
// ---------------------------------------------------------------------------
template <int K, int FUSE>
__launch_bounds__(256)
__global__ void gemm_kernel(const float* __restrict__ A, const float* __restrict__ B,
                            const float* __restrict__ bias, float* __restrict__ C,
                            unsigned* __restrict__ Cb, const float* __restrict__ att_s,
                            const float* __restrict__ att_d, float* __restrict__ asrc,
                            float* __restrict__ adst, int M) {
    __shared__ float Bs[K * 128];
    int t = threadIdx.x;
    const float4* B4 = (const float4*)B;
    float4* Bs4 = (float4*)Bs;
#pragma unroll
    for (int i = t; i < K * 32; i += 256) Bs4[i] = B4[i];
    __syncthreads();

    int c0 = (t & 15) * 8;
    int r0 = (t >> 4) * 4;
    int rbase = blockIdx.x * 64 + r0;

    float acc[4][8];
#pragma unroll
    for (int j = 0; j < 4; j++)
#pragma unroll
        for (int c = 0; c < 8; c++) acc[j][c] = 0.f;

    const float4* A4 = (const float4*)A;
    int rg[4];
#pragma unroll
    for (int j = 0; j < 4; j++) rg[j] = min(rbase + j, M - 1);

    for (int kk = 0; kk < K; kk += 4) {
        float4 av[4];
#pragma unroll
        for (int j = 0; j < 4; j++) av[j] = A4[(size_t)rg[j] * (K / 4) + (kk >> 2)];
        float a_arr[4][4];
#pragma unroll
        for (int j = 0; j < 4; j++) {
            a_arr[j][0] = av[j].x; a_arr[j][1] = av[j].y;
            a_arr[j][2] = av[j].z; a_arr[j][3] = av[j].w;
        }
#pragma unroll
        for (int jj = 0; jj < 4; jj++) {
            float4 b0 = Bs4[(kk + jj) * 32 + (c0 >> 2)];
            float4 b1 = Bs4[(kk + jj) * 32 + (c0 >> 2) + 1];
#pragma unroll
            for (int j = 0; j < 4; j++) {
                float a = a_arr[j][jj];
                acc[j][0] += a * b0.x; acc[j][1] += a * b0.y;
                acc[j][2] += a * b0.z; acc[j][3] += a * b0.w;
                acc[j][4] += a * b1.x; acc[j][5] += a * b1.y;
                acc[j][6] += a * b1.z; acc[j][7] += a * b1.w;
            }
        }
    }

    if (FUSE == 0) {
#pragma unroll
        for (int j = 0; j < 4; j++) {
            int r = rbase + j;
            if (r < M) {
                float4 o0, o1;
                o0.x = fmaxf(acc[j][0] + bias[c0 + 0], 0.f);
                o0.y = fmaxf(acc[j][1] + bias[c0 + 1], 0.f);
                o0.z = fmaxf(acc[j][2] + bias[c0 + 2], 0.f);
                o0.w = fmaxf(acc[j][3] + bias[c0 + 3], 0.f);
                o1.x = fmaxf(acc[j][4] + bias[c0 + 4], 0.f);
                o1.y = fmaxf(acc[j][5] + bias[c0 + 5], 0.f);
                o1.z = fmaxf(acc[j][6] + bias[c0 + 6], 0.f);
                o1.w = fmaxf(acc[j][7] + bias[c0 + 7], 0.f);
                ((float4*)(C + (size_t)r * 128 + c0))[0] = o0;
                ((float4*)(C + (size_t)r * 128 + c0 + 4))[0] = o1;
            }
        }
    } else {
        // attention-dot partials over this thread's 8 columns (single head)
        float as8[8], ad8[8];
#pragma unroll
        for (int c = 0; c < 8; c++) { as8[c] = att_s[c0 + c]; ad8[c] = att_d[c0 + c]; }
        int lane = t & 63;
        int h = (lane & 15) >> 2;
#pragma unroll
        for (int j = 0; j < 4; j++) {
            int r = rbase + j;
            // bf16 store of the projected row chunk.
            // Row = 64 dwords; channels c0..c0+7 live at dword offset c0/2.
            uint4 pk;
            pk.x = bf16pair(acc[j][0], acc[j][1]);
            pk.y = bf16pair(acc[j][2], acc[j][3]);
            pk.z = bf16pair(acc[j][4], acc[j][5]);
            pk.w = bf16pair(acc[j][6], acc[j][7]);
            float ps = 0.f, pd = 0.f;
#pragma unroll
            for (int c = 0; c < 8; c++) { ps += acc[j][c] * as8[c]; pd += acc[j][c] * ad8[c]; }
            // reduce over the 4 lanes covering this head's 32 channels
            ps += __shfl_xor(ps, 1); pd += __shfl_xor(pd, 1);
            ps += __shfl_xor(ps, 2); pd += __shfl_xor(pd, 2);
            if (r < M) {
                ((uint4*)(Cb + (size_t)r * 64 + (c0 >> 1)))[0] = pk;
                if ((lane & 3) == 0) {
                    asrc[r * 4 + h] = ps;
                    adst[r * 4 + h] = pd;
                }
            }
        }
    }
}

// ---------------------------------------------------------------------------
// Per-edge: ex = exp(leakyrelu(a_src+a_dst+a_edge)), scattered to CSR slot.
// Softmax is shift-invariant; logits are O(1) (clamped at 60) so unnormalized
// exp + divide in node_kernel is exact.
// ---------------------------------------------------------------------------
__launch_bounds__(256)
__global__ void edge_kernel(const int* __restrict__ src, const int* __restrict__ dst,
                            const float* __restrict__ ea, const float* __restrict__ asrc,
                            const float* __restrict__ adst, const float* __restrict__ wea,
                            const float* __restrict__ aloop, const int* __restrict__ epos,
                            float* __restrict__ exs) {
    int e = blockIdx.x * blockDim.x + threadIdx.x;
    if (e >= N_ETOT) return;
    int s, d;
    float ae0, ae1, ae2, ae3;
    if (e < N_EDGES) {
        s = src[e]; d = dst[e];
        ae0 = ae1 = ae2 = ae3 = 0.f;
        const float* er = ea + (size_t)e * ED;
#pragma unroll
        for (int dd = 0; dd < 12; dd++) {
            float v = er[dd];
            ae0 += v * wea[dd * 4 + 0];
            ae1 += v * wea[dd * 4 + 1];
            ae2 += v * wea[dd * 4 + 2];
            ae3 += v * wea[dd * 4 + 3];
        }
    } else {
        s = d = e - N_EDGES;
        ae0 = aloop[0]; ae1 = aloop[1]; ae2 = aloop[2]; ae3 = aloop[3];
    }
    float4 as = ((const float4*)asrc)[s];
    float4 ad = ((const float4*)adst)[d];
    float a0 = as.x + ad.x + ae0;
    float a1 = as.y + ad.y + ae1;
    float a2 = as.z + ad.z + ae2;
    float a3 = as.w + ad.w + ae3;
    a0 = (a0 > 0.f) ? a0 : 0.2f * a0;
    a1 = (a1 > 0.f) ? a1 : 0.2f * a1;
    a2 = (a2 > 0.f) ? a2 : 0.2f * a2;
    a3 = (a3 > 0.f) ? a3 : 0.2f * a3;
    float4 ex;
    ex.x = __expf(fminf(a0, 60.f));
    ex.y = __expf(fminf(a1, 60.f));
    ex.z = __expf(fminf(a2, 60.f));
    ex.w = __expf(fminf(a3, 60.f));
    ((float4*)exs)[epos[e]] = ex;
}

// ---------------------------------------------------------------------------
// Single-pass aggregation: one wave per destination node; lane owns channels
// 2*lane, 2*lane+1 (head h = lane>>4). xp rows are bf16-packed (1 dword/lane,
// 64 dwords/row). Unrolled x2 for gather MLP.
// ---------------------------------------------------------------------------
__launch_bounds__(256)
__global__ void node_kernel(const float* __restrict__ exs, const int* __restrict__ rowp,
                            const int* __restrict__ csr_src, const unsigned* __restrict__ xpb,
                            float* __restrict__ out) {
    int gw = (blockIdx.x * blockDim.x + threadIdx.x) >> 6;
    int lane = threadIdx.x & 63;
    if (gw >= N_NODES) return;
    int beg = rowp[gw], end = rowp[gw + 1];
    int h = lane >> 4;
    const float4* exs4 = (const float4*)exs;

    float accx = 0.f, accy = 0.f, den = 0.f;
    int j = beg;
    for (; j + 2 <= end; j += 2) {
        int s0 = csr_src[j], s1 = csr_src[j + 1];
        float4 e0 = exs4[j], e1 = exs4[j + 1];
        unsigned v0 = xpb[(size_t)s0 * 64 + lane];
        unsigned v1 = xpb[(size_t)s1 * 64 + lane];
        float ex0 = (h == 0) ? e0.x : (h == 1) ? e0.y : (h == 2) ? e0.z : e0.w;
        float ex1 = (h == 0) ? e1.x : (h == 1) ? e1.y : (h == 2) ? e1.z : e1.w;
        accx += ex0 * __uint_as_float(v0 << 16);
        accy += ex0 * __uint_as_float(v0 & 0xFFFF0000u);
        accx += ex1 * __uint_as_float(v1 << 16);
        accy += ex1 * __uint_as_float(v1 & 0xFFFF0000u);
        den += ex0 + ex1;
    }
    if (j < end) {
        int s0 = csr_src[j];
        float4 e0 = exs4[j];
        unsigned v0 = xpb[(size_t)s0 * 64 + lane];
        float ex0 = (h == 0) ? e0.x : (h == 1) ? e0.y : (h == 2) ? e0.z : e0.w;
        accx += ex0 * __uint_as_float(v0 << 16);
        accy += ex0 * __uint_as_float(v0 & 0xFFFF0000u);
        den += ex0;
    }
    float inv = 1.0f / den;
    ((float2*)out)[(size_t)gw * 64 + lane] = make_float2(accx * inv, accy * inv);
}

// ---------------------------------------------------------------------------
// BatchNorm statistics + fused update (BN finalize in-block, relu, residual)
// ---------------------------------------------------------------------------
__launch_bounds__(256)
__global__ void bnstats_kernel(const float* __restrict__ h, float* __restrict__ bnsum,
                               float* __restrict__ bnsum2) {
    __shared__ float ls[256], ls2[256];
    int t = threadIdx.x;
    int c = t & 127, half = t >> 7;
    int r0 = blockIdx.x * 128;
    float s = 0.f, s2 = 0.f;
    int rend = min(r0 + 128, N_NODES);
    for (int r = r0 + half; r < rend; r += 2) {
        float v = h[(size_t)r * 128 + c];
        s += v; s2 += v * v;
    }
    ls[t] = s; ls2[t] = s2;
    __syncthreads();
    if (half == 0) {
        s += ls[t + 128]; s2 += ls2[t + 128];
        atomicAdd(&bnsum[c], s);
        atomicAdd(&bnsum2[c], s2);
    }
}

__launch_bounds__(256)
__global__ void update_kernel(const float* __restrict__ outb, const float* __restrict__ bnsum,
                              const float* __restrict__ bnsum2, const float* __restrict__ gamma,
                              const float* __restrict__ beta, const float* __restrict__ hA,
                              float* __restrict__ dst, int add_res) {
    __shared__ float sc_s[128], sh_s[128];
    int t = threadIdx.x;
    if (t < 128) {
        float mu = bnsum[t] / (float)N_NODES;
        float var = bnsum2[t] / (float)N_NODES - mu * mu;
        float inv = rsqrtf(var + BN_EPS);
        float g = gamma[t] * inv;
        sc_s[t] = g;
        sh_s[t] = beta[t] - mu * g;
    }
    __syncthreads();
    int i = blockIdx.x * blockDim.x + t;
    if (i >= N_NODES * 32) return;
    int c4 = (i & 31) * 4;
    float4 o = ((const float4*)outb)[i];
    float4 v;
    v.x = fmaxf(o.x * sc_s[c4 + 0] + sh_s[c4 + 0], 0.f);
    v.y = fmaxf(o.y * sc_s[c4 + 1] + sh_s[c4 + 1], 0.f);
    v.z = fmaxf(o.z * sc_s[c4 + 2] + sh_s[c4 + 2], 0.f);
    v.w = fmaxf(o.w * sc_s[c4 + 3] + sh_s[c4 + 3], 0.f);
    if (add_res) {
        float4 hh = ((const float4*)hA)[i];
        v.x += hh.x; v.y += hh.y; v.z += hh.z; v.w += hh.w;
    }
    ((float4*)dst)[i] = v;
}

// ---------------------------------------------------------------------------
extern "C" void kernel_launch(void* const* d_in, const int* in_sizes, int n_in,
                              void* d_out, int out_size, void* d_ws, size_t ws_size,
                              hipStream_t stream) {
    const float* x          = (const float*)d_in[0];
    const int*   edge_index = (const int*)d_in[1];
    const float* edge_attr  = (const float*)d_in[2];
    const float* Wp         = (const float*)d_in[3];
    const float* bp         = (const float*)d_in[4];
    const float* W          = (const float*)d_in[5];
    const float* We         = (const float*)d_in[6];
    const float* att_src    = (const float*)d_in[7];
    const float* att_dst    = (const float*)d_in[8];
    const float* att_edge   = (const float*)d_in[9];
    // d_in[10] bias: absorbed exactly by training-mode BN -> skipped
    const float* gamma      = (const float*)d_in[11];
    const float* beta       = (const float*)d_in[12];
    float* outp = (float*)d_out;

    const int* ei_src = edge_index;
    const int* ei_dst = edge_index + N_EDGES;

    char* p = (char*)d_ws;
    auto alloc = [&](size_t nbytes) {
        char* r = p;
        p += (nbytes + 255) & ~(size_t)255;
        return r;
    };
    // zero-initialized region: hist | easum | bnsum(4 layers x 256)
    int*   hist     = (int*)alloc((size_t)N_NODES * 4);
    float* easum    = (float*)alloc(16 * 4);
    float* bnsumall = (float*)alloc((size_t)LAYERS * 256 * 4);
    size_t zero_bytes = (char*)(bnsumall + LAYERS * 256) - (char*)hist;

    float* hA       = (float*)alloc((size_t)N_NODES * 128 * 4);
    unsigned* xpb   = (unsigned*)alloc((size_t)N_NODES * 64 * 4);   // bf16x2 per dword
    float* outb     = (float*)alloc((size_t)N_NODES * 128 * 4);
    float* exs      = (float*)alloc((size_t)N_ETOT * 4 * 4);
    float* asrc     = (float*)alloc((size_t)N_NODES * 4 * 4);
    float* adst     = (float*)alloc((size_t)N_NODES * 4 * 4);
    float* wea_all  = (float*)alloc((LAYERS * 48 + 16) * 4);
    float* aloop    = wea_all + LAYERS * 48;
    int* rowp       = (int*)alloc(((size_t)N_NODES + 1) * 4);
    int* cursor     = (int*)alloc((size_t)N_NODES * 4);
    int* epos       = (int*)alloc((size_t)N_ETOT * 4);
    int* csr_src    = (int*)alloc((size_t)N_ETOT * 4);
    int* bsum       = (int*)alloc(256 * 4);
    int* boff       = (int*)alloc(256 * 4);

    const int EB = (N_ETOT + 255) / 256;

    hipMemsetAsync(hist, 0, zero_bytes, stream);

    // ---- CSR build (graph fixed across layers) ----
    hist_kernel<<<EB, 256, 0, stream>>>(ei_dst, hist);
    blocksum_kernel<<<SCAN_BLK, 256, 0, stream>>>(hist, bsum);
    bscan_kernel<<<1, 256, 0, stream>>>(bsum, boff, rowp);
    rowp_kernel<<<SCAN_BLK, 256, 0, stream>>>(hist, boff, rowp, cursor);
    scatter_kernel<<<EB, 256, 0, stream>>>(ei_src, ei_dst, cursor, epos, csr_src);

    // ---- edge-attr mean + folded edge-attention matrices (all layers) ----
    eamean_kernel<<<256, 256, 0, stream>>>(edge_attr, easum);
    prep_kernel<<<1, 256, 0, stream>>>(easum, We, att_edge, wea_all, aloop);

    // ---- initial projection (f32 out, bias+relu) ----
    gemm_kernel<64, 0><<<(N_NODES + 63) / 64, 256, 0, stream>>>(
        x, Wp, bp, hA, nullptr, nullptr, nullptr, nullptr, nullptr, N_NODES);

    for (int l = 0; l < LAYERS; l++) {
        float* bnsum  = bnsumall + l * 256;
        float* bnsum2 = bnsum + 128;
        gemm_kernel<128, 1><<<(N_NODES + 63) / 64, 256, 0, stream>>>(
            hA, W + (size_t)l * 128 * 128, nullptr, nullptr, xpb,
            att_src + l * 128, att_dst + l * 128, asrc, adst, N_NODES);
        edge_kernel<<<EB, 256, 0, stream>>>(ei_src, ei_dst, edge_attr, asrc, adst,
                                            wea_all + l * 48, aloop + l * 4, epos, exs);
        node_kernel<<<(N_NODES + 3) / 4, 256, 0, stream>>>(exs, rowp, csr_src, xpb, outb);
        bnstats_kernel<<<(N_NODES + 127) / 128, 256, 0, stream>>>(outb, bnsum, bnsum2);
        float* dst = (l == LAYERS - 1) ? outp : hA;
        update_kernel<<<(N_NODES * 32 + 255) / 256, 256, 0, stream>>>(
            outb, bnsum, bnsum2, gamma + l * 128, beta + l * 128, hA, dst, (l > 0) ? 1 : 0);
    }
}

// Round 5
// 872.162 us; speedup vs baseline: 1.4055x; 1.0844x over previous
//
#include <hip/hip_runtime.h>

// Problem constants (match reference setup_inputs)
constexpr int N_NODES = 50000;
constexpr int N_EDGES = 800000;
constexpr int N_ETOT  = N_EDGES + N_NODES;   // with self loops
constexpr int HID     = 128;
constexpr int HEADS   = 4;
constexpr int ED      = 12;
constexpr int LAYERS  = 4;
constexpr float BN_EPS = 1e-5f;
constexpr int SCAN_BLK = (N_NODES + 255) / 256;   // 196

__device__ inline unsigned bf16pair(float a, float b) {
    unsigned ua = __float_as_uint(a), ub = __float_as_uint(b);
    ua = (ua + 0x7FFFu + ((ua >> 16) & 1u)) >> 16;
    ub = (ub + 0x7FFFu + ((ub >> 16) & 1u)) >> 16;
    return ua | (ub << 16);
}

// ---------------------------------------------------------------------------
// CSR build: histogram of dst, multi-block scan, scatter (stores epos[e])
// ---------------------------------------------------------------------------
__global__ void hist_kernel(const int* __restrict__ dst, int* __restrict__ hist) {
    int e = blockIdx.x * blockDim.x + threadIdx.x;
    if (e >= N_ETOT) return;
    int d = (e < N_EDGES) ? dst[e] : (e - N_EDGES);
    atomicAdd(&hist[d], 1);
}

__global__ void blocksum_kernel(const int* __restrict__ hist, int* __restrict__ bsum) {
    __shared__ int sd[256];
    int t = threadIdx.x;
    int n = blockIdx.x * 256 + t;
    sd[t] = (n < N_NODES) ? hist[n] : 0;
    __syncthreads();
#pragma unroll
    for (int off = 128; off; off >>= 1) {
        if (t < off) sd[t] += sd[t + off];
        __syncthreads();
    }
    if (t == 0) bsum[blockIdx.x] = sd[0];
}

__global__ void bscan_kernel(const int* __restrict__ bsum, int* __restrict__ boff,
                             int* __restrict__ rowp) {
    __shared__ int sd[256];
    int t = threadIdx.x;
    int v = (t < SCAN_BLK) ? bsum[t] : 0;
    sd[t] = v;
    __syncthreads();
#pragma unroll
    for (int off = 1; off < 256; off <<= 1) {
        int u = (t >= off) ? sd[t - off] : 0;
        __syncthreads();
        sd[t] += u;
        __syncthreads();
    }
    if (t < SCAN_BLK) boff[t] = sd[t] - v;
    if (t == 255) rowp[N_NODES] = sd[255];
}

__global__ void rowp_kernel(const int* __restrict__ hist, const int* __restrict__ boff,
                            int* __restrict__ rowp, int* __restrict__ cursor) {
    __shared__ int sd[256];
    int t = threadIdx.x;
    int n = blockIdx.x * 256 + t;
    int v = (n < N_NODES) ? hist[n] : 0;
    sd[t] = v;
    __syncthreads();
#pragma unroll
    for (int off = 1; off < 256; off <<= 1) {
        int u = (t >= off) ? sd[t - off] : 0;
        __syncthreads();
        sd[t] += u;
        __syncthreads();
    }
    if (n < N_NODES) {
        int excl = sd[t] - v + boff[blockIdx.x];
        rowp[n] = excl;
        cursor[n] = excl;
    }
}

__global__ void scatter_kernel(const int* __restrict__ src, const int* __restrict__ dst,
                               int* __restrict__ cursor, int* __restrict__ epos,
                               int* __restrict__ csr_src) {
    int e = blockIdx.x * blockDim.x + threadIdx.x;
    if (e >= N_ETOT) return;
    int s, d;
    if (e < N_EDGES) { s = src[e]; d = dst[e]; }
    else             { s = d = e - N_EDGES; }
    int pos = atomicAdd(&cursor[d], 1);
    epos[e] = pos;
    csr_src[pos] = s;
}

// ---------------------------------------------------------------------------
// edge_attr mean (over real edges) -> easum[12]
// ---------------------------------------------------------------------------
__launch_bounds__(256)
__global__ void eamean_kernel(const float* __restrict__ ea, float* __restrict__ easum) {
    __shared__ float ls[12];
    int t = threadIdx.x;
    if (t < 12) ls[t] = 0.f;
    __syncthreads();
    float loc[12];
#pragma unroll
    for (int d = 0; d < 12; d++) loc[d] = 0.f;
    int stride = gridDim.x * 256;
    for (int e = blockIdx.x * 256 + t; e < N_EDGES; e += stride) {
        const float* er = ea + (size_t)e * ED;
#pragma unroll
        for (int d = 0; d < 12; d++) loc[d] += er[d];
    }
#pragma unroll
    for (int d = 0; d < 12; d++) atomicAdd(&ls[d], loc[d]);
    __syncthreads();
    if (t < 12) atomicAdd(&easum[t], ls[t]);
}

__global__ void prep_kernel(const float* __restrict__ easum, const float* __restrict__ We,
                            const float* __restrict__ att_edge, float* __restrict__ wea_all,
                            float* __restrict__ aloop) {
    __shared__ float em[12];
    __shared__ float weash[LAYERS * ED * HEADS];
    int t = threadIdx.x;
    if (t < 12) em[t] = easum[t] / (float)N_EDGES;
    if (t < LAYERS * ED * HEADS) {
        int l = t / (ED * HEADS);
        int r = t % (ED * HEADS);
        int d = r / HEADS;
        int h = r % HEADS;
        float sum = 0.f;
#pragma unroll
        for (int c = 0; c < 32; c++)
            sum += We[((size_t)(l * ED + d)) * HID + h * 32 + c] *
                   att_edge[(l * HEADS + h) * 32 + c];
        wea_all[t] = sum;
        weash[t] = sum;
    }
    __syncthreads();
    if (t < LAYERS * HEADS) {
        int l = t / HEADS, h = t % HEADS;
        float s = 0.f;
#pragma unroll
        for (int d = 0; d < 12; d++) s += em[d] * weash[l * ED * HEADS + d * HEADS + h];
        aloop[t] = s;
    }
}

// ---------------------------------------------------------------------------
// GEMM: [M,K]@[K,128]. FUSE=0: f32 out + bias + relu (initial projection).
// FUSE=1: bf16 out (xpb, 64 dwords/row) + fused attention dots asrc/adst.
// Block: 256 threads -> 64 rows x 128 cols; thread: 4 rows x 8 cols.
// ---------------------------------------------------------------------------
template <int K, int FUSE>
__launch_bounds__(256)
__global__ void gemm_kernel(const float* __restrict__ A, const float* __restrict__ B,
                            const float* __restrict__ bias, float* __restrict__ C,
                            unsigned* __restrict__ Cb, const float* __restrict__ att_s,
                            const float* __restrict__ att_d, float* __restrict__ asrc,
                            float* __restrict__ adst, int M) {
    __shared__ float Bs[K * 128];
    int t = threadIdx.x;
    const float4* B4 = (const float4*)B;
    float4* Bs4 = (float4*)Bs;
#pragma unroll
    for (int i = t; i < K * 32; i += 256) Bs4[i] = B4[i];
    __syncthreads();

    int c0 = (t & 15) * 8;
    int r0 = (t >> 4) * 4;
    int rbase = blockIdx.x * 64 + r0;

    float acc[4][8];
#pragma unroll
    for (int j = 0; j < 4; j++)
#pragma unroll
        for (int c = 0; c < 8; c++) acc[j][c] = 0.f;

    const float4* A4 = (const float4*)A;
    int rg[4];
#pragma unroll
    for (int j = 0; j < 4; j++) rg[j] = min(rbase + j, M - 1);

    for (int kk = 0; kk < K; kk += 4) {
        float4 av[4];
#pragma unroll
        for (int j = 0; j < 4; j++) av[j] = A4[(size_t)rg[j] * (K / 4) + (kk >> 2)];
        float a_arr[4][4];
#pragma unroll
        for (int j = 0; j < 4; j++) {
            a_arr[j][0] = av[j].x; a_arr[j][1] = av[j].y;
            a_arr[j][2] = av[j].z; a_arr[j][3] = av[j].w;
        }
#pragma unroll
        for (int jj = 0; jj < 4; jj++) {
            float4 b0 = Bs4[(kk + jj) * 32 + (c0 >> 2)];
            float4 b1 = Bs4[(kk + jj) * 32 + (c0 >> 2) + 1];
#pragma unroll
            for (int j = 0; j < 4; j++) {
                float a = a_arr[j][jj];
                acc[j][0] += a * b0.x; acc[j][1] += a * b0.y;
                acc[j][2] += a * b0.z; acc[j][3] += a * b0.w;
                acc[j][4] += a * b1.x; acc[j][5] += a * b1.y;
                acc[j][6] += a * b1.z; acc[j][7] += a * b1.w;
            }
        }
    }

    if (FUSE == 0) {
#pragma unroll
        for (int j = 0; j < 4; j++) {
            int r = rbase + j;
            if (r < M) {
                float4 o0, o1;
                o0.x = fmaxf(acc[j][0] + bias[c0 + 0], 0.f);
                o0.y = fmaxf(acc[j][1] + bias[c0 + 1], 0.f);
                o0.z = fmaxf(acc[j][2] + bias[c0 + 2], 0.f);
                o0.w = fmaxf(acc[j][3] + bias[c0 + 3], 0.f);
                o1.x = fmaxf(acc[j][4] + bias[c0 + 4], 0.f);
                o1.y = fmaxf(acc[j][5] + bias[c0 + 5], 0.f);
                o1.z = fmaxf(acc[j][6] + bias[c0 + 6], 0.f);
                o1.w = fmaxf(acc[j][7] + bias[c0 + 7], 0.f);
                ((float4*)(C + (size_t)r * 128 + c0))[0] = o0;
                ((float4*)(C + (size_t)r * 128 + c0 + 4))[0] = o1;
            }
        }
    } else {
        // attention-dot partials over this thread's 8 columns (single head)
        float as8[8], ad8[8];
#pragma unroll
        for (int c = 0; c < 8; c++) { as8[c] = att_s[c0 + c]; ad8[c] = att_d[c0 + c]; }
        int lane = t & 63;
        int h = (lane & 15) >> 2;
#pragma unroll
        for (int j = 0; j < 4; j++) {
            int r = rbase + j;
            // bf16 store of the projected row chunk.
            // Row = 64 dwords; channels c0..c0+7 live at dword offset c0/2.
            uint4 pk;
            pk.x = bf16pair(acc[j][0], acc[j][1]);
            pk.y = bf16pair(acc[j][2], acc[j][3]);
            pk.z = bf16pair(acc[j][4], acc[j][5]);
            pk.w = bf16pair(acc[j][6], acc[j][7]);
            float ps = 0.f, pd = 0.f;
#pragma unroll
            for (int c = 0; c < 8; c++) { ps += acc[j][c] * as8[c]; pd += acc[j][c] * ad8[c]; }
            // reduce over the 4 lanes covering this head's 32 channels
            ps += __shfl_xor(ps, 1); pd += __shfl_xor(pd, 1);
            ps += __shfl_xor(ps, 2); pd += __shfl_xor(pd, 2);
            if (r < M) {
                ((uint4*)(Cb + (size_t)r * 64 + (c0 >> 1)))[0] = pk;
                if ((lane & 3) == 0) {
                    asrc[r * 4 + h] = ps;
                    adst[r * 4 + h] = pd;
                }
            }
        }
    }
}

// ---------------------------------------------------------------------------
// Per-edge: ex = exp(leakyrelu(a_src+a_dst+a_edge)), scattered to CSR slot.
// Softmax is shift-invariant; logits are O(1) (clamped at 60) so unnormalized
// exp + divide in node_kernel is exact.
// ---------------------------------------------------------------------------
__launch_bounds__(256)
__global__ void edge_kernel(const int* __restrict__ src, const int* __restrict__ dst,
                            const float* __restrict__ ea, const float* __restrict__ asrc,
                            const float* __restrict__ adst, const float* __restrict__ wea,
                            const float* __restrict__ aloop, const int* __restrict__ epos,
                            float* __restrict__ exs) {
    int e = blockIdx.x * blockDim.x + threadIdx.x;
    if (e >= N_ETOT) return;
    int s, d;
    float ae0, ae1, ae2, ae3;
    if (e < N_EDGES) {
        s = src[e]; d = dst[e];
        ae0 = ae1 = ae2 = ae3 = 0.f;
        const float* er = ea + (size_t)e * ED;
#pragma unroll
        for (int dd = 0; dd < 12; dd++) {
            float v = er[dd];
            ae0 += v * wea[dd * 4 + 0];
            ae1 += v * wea[dd * 4 + 1];
            ae2 += v * wea[dd * 4 + 2];
            ae3 += v * wea[dd * 4 + 3];
        }
    } else {
        s = d = e - N_EDGES;
        ae0 = aloop[0]; ae1 = aloop[1]; ae2 = aloop[2]; ae3 = aloop[3];
    }
    float4 as = ((const float4*)asrc)[s];
    float4 ad = ((const float4*)adst)[d];
    float a0 = as.x + ad.x + ae0;
    float a1 = as.y + ad.y + ae1;
    float a2 = as.z + ad.z + ae2;
    float a3 = as.w + ad.w + ae3;
    a0 = (a0 > 0.f) ? a0 : 0.2f * a0;
    a1 = (a1 > 0.f) ? a1 : 0.2f * a1;
    a2 = (a2 > 0.f) ? a2 : 0.2f * a2;
    a3 = (a3 > 0.f) ? a3 : 0.2f * a3;
    float4 ex;
    ex.x = __expf(fminf(a0, 60.f));
    ex.y = __expf(fminf(a1, 60.f));
    ex.z = __expf(fminf(a2, 60.f));
    ex.w = __expf(fminf(a3, 60.f));
    ((float4*)exs)[epos[e]] = ex;
}

// ---------------------------------------------------------------------------
// Single-pass aggregation: one wave per destination node, HALF-WAVE per edge.
// lane = 32*sub + sl: sub picks edge j+sub, sl covers the 128-ch bf16 row as
// uint2 (4 channels/lane). One dwordx2 load fetches TWO edges' rows (512 B);
// unroll x2 puts 4 edges in flight. Halves combine via shfl_xor(32) at end.
// ---------------------------------------------------------------------------
__launch_bounds__(256)
__global__ void node_kernel(const float* __restrict__ exs, const int* __restrict__ rowp,
                            const int* __restrict__ csr_src, const unsigned* __restrict__ xpb,
                            float* __restrict__ out) {
    int gw = (blockIdx.x * blockDim.x + threadIdx.x) >> 6;
    int lane = threadIdx.x & 63;
    if (gw >= N_NODES) return;
    int sub = lane >> 5;   // which edge of the pair
    int sl  = lane & 31;   // channel quad: channels 4*sl..4*sl+3
    int h   = sl >> 3;     // head
    int beg = rowp[gw], end = rowp[gw + 1];
    const float4* exs4 = (const float4*)exs;
    const uint2* xp2 = (const uint2*)xpb;

    float a0 = 0.f, a1 = 0.f, a2 = 0.f, a3 = 0.f, den = 0.f;
    int j = beg + sub;
    for (; j + 2 < end; j += 4) {
        int s0 = csr_src[j];
        int s1 = csr_src[j + 2];
        float4 e0 = exs4[j];
        float4 e1 = exs4[j + 2];
        uint2 v0 = xp2[(size_t)s0 * 32 + sl];
        uint2 v1 = xp2[(size_t)s1 * 32 + sl];
        float ex0 = (h == 0) ? e0.x : (h == 1) ? e0.y : (h == 2) ? e0.z : e0.w;
        float ex1 = (h == 0) ? e1.x : (h == 1) ? e1.y : (h == 2) ? e1.z : e1.w;
        a0 += ex0 * __uint_as_float(v0.x << 16);
        a1 += ex0 * __uint_as_float(v0.x & 0xFFFF0000u);
        a2 += ex0 * __uint_as_float(v0.y << 16);
        a3 += ex0 * __uint_as_float(v0.y & 0xFFFF0000u);
        a0 += ex1 * __uint_as_float(v1.x << 16);
        a1 += ex1 * __uint_as_float(v1.x & 0xFFFF0000u);
        a2 += ex1 * __uint_as_float(v1.y << 16);
        a3 += ex1 * __uint_as_float(v1.y & 0xFFFF0000u);
        den += ex0 + ex1;
    }
    if (j < end) {
        int s0 = csr_src[j];
        float4 e0 = exs4[j];
        uint2 v0 = xp2[(size_t)s0 * 32 + sl];
        float ex0 = (h == 0) ? e0.x : (h == 1) ? e0.y : (h == 2) ? e0.z : e0.w;
        a0 += ex0 * __uint_as_float(v0.x << 16);
        a1 += ex0 * __uint_as_float(v0.x & 0xFFFF0000u);
        a2 += ex0 * __uint_as_float(v0.y << 16);
        a3 += ex0 * __uint_as_float(v0.y & 0xFFFF0000u);
        den += ex0;
    }
    // combine the two half-waves
    a0 += __shfl_xor(a0, 32);
    a1 += __shfl_xor(a1, 32);
    a2 += __shfl_xor(a2, 32);
    a3 += __shfl_xor(a3, 32);
    den += __shfl_xor(den, 32);
    float inv = 1.0f / den;   // deg >= 1 (self loop)
    if (sub == 0)
        ((float4*)out)[(size_t)gw * 32 + sl] = make_float4(a0 * inv, a1 * inv, a2 * inv, a3 * inv);
}

// ---------------------------------------------------------------------------
// BatchNorm statistics + fused update (BN finalize in-block, relu, residual)
// ---------------------------------------------------------------------------
__launch_bounds__(256)
__global__ void bnstats_kernel(const float* __restrict__ h, float* __restrict__ bnsum,
                               float* __restrict__ bnsum2) {
    __shared__ float ls[256], ls2[256];
    int t = threadIdx.x;
    int c = t & 127, half = t >> 7;
    int r0 = blockIdx.x * 128;
    float s = 0.f, s2 = 0.f;
    int rend = min(r0 + 128, N_NODES);
    for (int r = r0 + half; r < rend; r += 2) {
        float v = h[(size_t)r * 128 + c];
        s += v; s2 += v * v;
    }
    ls[t] = s; ls2[t] = s2;
    __syncthreads();
    if (half == 0) {
        s += ls[t + 128]; s2 += ls2[t + 128];
        atomicAdd(&bnsum[c], s);
        atomicAdd(&bnsum2[c], s2);
    }
}

__launch_bounds__(256)
__global__ void update_kernel(const float* __restrict__ outb, const float* __restrict__ bnsum,
                              const float* __restrict__ bnsum2, const float* __restrict__ gamma,
                              const float* __restrict__ beta, const float* __restrict__ hA,
                              float* __restrict__ dst, int add_res) {
    __shared__ float sc_s[128], sh_s[128];
    int t = threadIdx.x;
    if (t < 128) {
        float mu = bnsum[t] / (float)N_NODES;
        float var = bnsum2[t] / (float)N_NODES - mu * mu;
        float inv = rsqrtf(var + BN_EPS);
        float g = gamma[t] * inv;
        sc_s[t] = g;
        sh_s[t] = beta[t] - mu * g;
    }
    __syncthreads();
    int i = blockIdx.x * blockDim.x + t;
    if (i >= N_NODES * 32) return;
    int c4 = (i & 31) * 4;
    float4 o = ((const float4*)outb)[i];
    float4 v;
    v.x = fmaxf(o.x * sc_s[c4 + 0] + sh_s[c4 + 0], 0.f);
    v.y = fmaxf(o.y * sc_s[c4 + 1] + sh_s[c4 + 1], 0.f);
    v.z = fmaxf(o.z * sc_s[c4 + 2] + sh_s[c4 + 2], 0.f);
    v.w = fmaxf(o.w * sc_s[c4 + 3] + sh_s[c4 + 3], 0.f);
    if (add_res) {
        float4 hh = ((const float4*)hA)[i];
        v.x += hh.x; v.y += hh.y; v.z += hh.z; v.w += hh.w;
    }
    ((float4*)dst)[i] = v;
}

// ---------------------------------------------------------------------------
extern "C" void kernel_launch(void* const* d_in, const int* in_sizes, int n_in,
                              void* d_out, int out_size, void* d_ws, size_t ws_size,
                              hipStream_t stream) {
    const float* x          = (const float*)d_in[0];
    const int*   edge_index = (const int*)d_in[1];
    const float* edge_attr  = (const float*)d_in[2];
    const float* Wp         = (const float*)d_in[3];
    const float* bp         = (const float*)d_in[4];
    const float* W          = (const float*)d_in[5];
    const float* We         = (const float*)d_in[6];
    const float* att_src    = (const float*)d_in[7];
    const float* att_dst    = (const float*)d_in[8];
    const float* att_edge   = (const float*)d_in[9];
    // d_in[10] bias: absorbed exactly by training-mode BN -> skipped
    const float* gamma      = (const float*)d_in[11];
    const float* beta       = (const float*)d_in[12];
    float* outp = (float*)d_out;

    const int* ei_src = edge_index;
    const int* ei_dst = edge_index + N_EDGES;

    char* p = (char*)d_ws;
    auto alloc = [&](size_t nbytes) {
        char* r = p;
        p += (nbytes + 255) & ~(size_t)255;
        return r;
    };
    // zero-initialized region: hist | easum | bnsum(4 layers x 256)
    int*   hist     = (int*)alloc((size_t)N_NODES * 4);
    float* easum    = (float*)alloc(16 * 4);
    float* bnsumall = (float*)alloc((size_t)LAYERS * 256 * 4);
    size_t zero_bytes = (char*)(bnsumall + LAYERS * 256) - (char*)hist;

    float* hA       = (float*)alloc((size_t)N_NODES * 128 * 4);
    unsigned* xpb   = (unsigned*)alloc((size_t)N_NODES * 64 * 4);   // bf16x2 per dword
    float* outb     = (float*)alloc((size_t)N_NODES * 128 * 4);
    float* exs      = (float*)alloc((size_t)N_ETOT * 4 * 4);
    float* asrc     = (float*)alloc((size_t)N_NODES * 4 * 4);
    float* adst     = (float*)alloc((size_t)N_NODES * 4 * 4);
    float* wea_all  = (float*)alloc((LAYERS * 48 + 16) * 4);
    float* aloop    = wea_all + LAYERS * 48;
    int* rowp       = (int*)alloc(((size_t)N_NODES + 1) * 4);
    int* cursor     = (int*)alloc((size_t)N_NODES * 4);
    int* epos       = (int*)alloc((size_t)N_ETOT * 4);
    int* csr_src    = (int*)alloc((size_t)N_ETOT * 4);
    int* bsum       = (int*)alloc(256 * 4);
    int* boff       = (int*)alloc(256 * 4);

    const int EB = (N_ETOT + 255) / 256;

    hipMemsetAsync(hist, 0, zero_bytes, stream);

    // ---- CSR build (graph fixed across layers) ----
    hist_kernel<<<EB, 256, 0, stream>>>(ei_dst, hist);
    blocksum_kernel<<<SCAN_BLK, 256, 0, stream>>>(hist, bsum);
    bscan_kernel<<<1, 256, 0, stream>>>(bsum, boff, rowp);
    rowp_kernel<<<SCAN_BLK, 256, 0, stream>>>(hist, boff, rowp, cursor);
    scatter_kernel<<<EB, 256, 0, stream>>>(ei_src, ei_dst, cursor, epos, csr_src);

    // ---- edge-attr mean + folded edge-attention matrices (all layers) ----
    eamean_kernel<<<256, 256, 0, stream>>>(edge_attr, easum);
    prep_kernel<<<1, 256, 0, stream>>>(easum, We, att_edge, wea_all, aloop);

    // ---- initial projection (f32 out, bias+relu) ----
    gemm_kernel<64, 0><<<(N_NODES + 63) / 64, 256, 0, stream>>>(
        x, Wp, bp, hA, nullptr, nullptr, nullptr, nullptr, nullptr, N_NODES);

    for (int l = 0; l < LAYERS; l++) {
        float* bnsum  = bnsumall + l * 256;
        float* bnsum2 = bnsum + 128;
        gemm_kernel<128, 1><<<(N_NODES + 63) / 64, 256, 0, stream>>>(
            hA, W + (size_t)l * 128 * 128, nullptr, nullptr, xpb,
            att_src + l * 128, att_dst + l * 128, asrc, adst, N_NODES);
        edge_kernel<<<EB, 256, 0, stream>>>(ei_src, ei_dst, edge_attr, asrc, adst,
                                            wea_all + l * 48, aloop + l * 4, epos, exs);
        node_kernel<<<(N_NODES + 3) / 4, 256, 0, stream>>>(exs, rowp, csr_src, xpb, outb);
        bnstats_kernel<<<(N_NODES + 127) / 128, 256, 0, stream>>>(outb, bnsum, bnsum2);
        float* dst = (l == LAYERS - 1) ? outp : hA;
        update_kernel<<<(N_NODES * 32 + 255) / 256, 256, 0, stream>>>(
            outb, bnsum, bnsum2, gamma + l * 128, beta + l * 128, hA, dst, (l > 0) ? 1 : 0);
    }
}

// Round 7
// 740.383 us; speedup vs baseline: 1.6557x; 1.1780x over previous
//
#include <hip/hip_runtime.h>

// Problem constants (match reference setup_inputs)
constexpr int N_NODES = 50000;
constexpr int N_EDGES = 800000;
constexpr int N_ETOT  = N_EDGES + N_NODES;   // with self loops
constexpr int HID     = 128;
constexpr int HEADS   = 4;
constexpr int ED      = 12;
constexpr int LAYERS  = 4;
constexpr float BN_EPS = 1e-5f;
constexpr int SCAN_BLK = (N_NODES + 255) / 256;   // 196

typedef __attribute__((ext_vector_type(8))) short short8;
typedef __attribute__((ext_vector_type(4))) float floatx4;

__device__ inline unsigned bf16pair(float a, float b) {
    unsigned ua = __float_as_uint(a), ub = __float_as_uint(b);
    ua = (ua + 0x7FFFu + ((ua >> 16) & 1u)) >> 16;
    ub = (ub + 0x7FFFu + ((ub >> 16) & 1u)) >> 16;
    return ua | (ub << 16);
}

// ---------------------------------------------------------------------------
// CSR build: histogram of dst, multi-block scan, scatter (stores epos[e])
// ---------------------------------------------------------------------------
__global__ void hist_kernel(const int* __restrict__ dst, int* __restrict__ hist) {
    int e = blockIdx.x * blockDim.x + threadIdx.x;
    if (e >= N_ETOT) return;
    int d = (e < N_EDGES) ? dst[e] : (e - N_EDGES);
    atomicAdd(&hist[d], 1);
}

__global__ void blocksum_kernel(const int* __restrict__ hist, int* __restrict__ bsum) {
    __shared__ int sd[256];
    int t = threadIdx.x;
    int n = blockIdx.x * 256 + t;
    sd[t] = (n < N_NODES) ? hist[n] : 0;
    __syncthreads();
#pragma unroll
    for (int off = 128; off; off >>= 1) {
        if (t < off) sd[t] += sd[t + off];
        __syncthreads();
    }
    if (t == 0) bsum[blockIdx.x] = sd[0];
}

__global__ void bscan_kernel(const int* __restrict__ bsum, int* __restrict__ boff,
                             int* __restrict__ rowp) {
    __shared__ int sd[256];
    int t = threadIdx.x;
    int v = (t < SCAN_BLK) ? bsum[t] : 0;
    sd[t] = v;
    __syncthreads();
#pragma unroll
    for (int off = 1; off < 256; off <<= 1) {
        int u = (t >= off) ? sd[t - off] : 0;
        __syncthreads();
        sd[t] += u;
        __syncthreads();
    }
    if (t < SCAN_BLK) boff[t] = sd[t] - v;
    if (t == 255) rowp[N_NODES] = sd[255];
}

__global__ void rowp_kernel(const int* __restrict__ hist, const int* __restrict__ boff,
                            int* __restrict__ rowp, int* __restrict__ cursor) {
    __shared__ int sd[256];
    int t = threadIdx.x;
    int n = blockIdx.x * 256 + t;
    int v = (n < N_NODES) ? hist[n] : 0;
    sd[t] = v;
    __syncthreads();
#pragma unroll
    for (int off = 1; off < 256; off <<= 1) {
        int u = (t >= off) ? sd[t - off] : 0;
        __syncthreads();
        sd[t] += u;
        __syncthreads();
    }
    if (n < N_NODES) {
        int excl = sd[t] - v + boff[blockIdx.x];
        rowp[n] = excl;
        cursor[n] = excl;
    }
}

__global__ void scatter_kernel(const int* __restrict__ src, const int* __restrict__ dst,
                               int* __restrict__ cursor, int* __restrict__ epos,
                               int* __restrict__ csr_src) {
    int e = blockIdx.x * blockDim.x + threadIdx.x;
    if (e >= N_ETOT) return;
    int s, d;
    if (e < N_EDGES) { s = src[e]; d = dst[e]; }
    else             { s = d = e - N_EDGES; }
    int pos = atomicAdd(&cursor[d], 1);
    epos[e] = pos;
    csr_src[pos] = s;
}

// ---------------------------------------------------------------------------
// edge_attr mean (over real edges) -> easum[12]
// ---------------------------------------------------------------------------
__launch_bounds__(256)
__global__ void eamean_kernel(const float* __restrict__ ea, float* __restrict__ easum) {
    __shared__ float ls[12];
    int t = threadIdx.x;
    if (t < 12) ls[t] = 0.f;
    __syncthreads();
    float loc[12];
#pragma unroll
    for (int d = 0; d < 12; d++) loc[d] = 0.f;
    int stride = gridDim.x * 256;
    for (int e = blockIdx.x * 256 + t; e < N_EDGES; e += stride) {
        const float* er = ea + (size_t)e * ED;
#pragma unroll
        for (int d = 0; d < 12; d++) loc[d] += er[d];
    }
#pragma unroll
    for (int d = 0; d < 12; d++) atomicAdd(&ls[d], loc[d]);
    __syncthreads();
    if (t < 12) atomicAdd(&easum[t], ls[t]);
}

__global__ void prep_kernel(const float* __restrict__ easum, const float* __restrict__ We,
                            const float* __restrict__ att_edge, float* __restrict__ wea_all,
                            float* __restrict__ aloop) {
    __shared__ float em[12];
    __shared__ float weash[LAYERS * ED * HEADS];
    int t = threadIdx.x;
    if (t < 12) em[t] = easum[t] / (float)N_EDGES;
    if (t < LAYERS * ED * HEADS) {
        int l = t / (ED * HEADS);
        int r = t % (ED * HEADS);
        int d = r / HEADS;
        int h = r % HEADS;
        float sum = 0.f;
#pragma unroll
        for (int c = 0; c < 32; c++)
            sum += We[((size_t)(l * ED + d)) * HID + h * 32 + c] *
                   att_edge[(l * HEADS + h) * 32 + c];
        wea_all[t] = sum;
        weash[t] = sum;
    }
    __syncthreads();
    if (t < LAYERS * HEADS) {
        int l = t / HEADS, h = t % HEADS;
        float s = 0.f;
#pragma unroll
        for (int d = 0; d < 12; d++) s += em[d] * weash[l * ED * HEADS + d * HEADS + h];
        aloop[t] = s;
    }
}

// ---------------------------------------------------------------------------
// Pack all layer weights W[l][k][n] (f32) into per-lane MFMA B-fragment order:
// wb[l][(kt*8+nt)*64 + lane][j] = bf16(W[kt*32+quad*8+j][nt*16+(lane&15)]),
// lane = quad*16 + c. 32 KB/layer -> L2-resident, read directly (no LDS).
// ---------------------------------------------------------------------------
__global__ void packW_kernel(const float* __restrict__ W, unsigned short* __restrict__ wb) {
    int idx = blockIdx.x * 256 + threadIdx.x;
    if (idx >= LAYERS * HID * HID) return;
    int l = idx >> 14;
    int k = (idx >> 7) & 127;
    int n = idx & 127;
    unsigned u = __float_as_uint(W[idx]);
    u = (u + 0x7FFFu + ((u >> 16) & 1u)) >> 16;
    int kt = k >> 5, q = (k & 31) >> 3, j = k & 7;
    int nt = n >> 4, c = n & 15;
    int lane = q * 16 + c;
    wb[(size_t)l * 16384 + ((size_t)(kt * 8 + nt) * 64 + lane) * 8 + j] = (unsigned short)u;
}

// ---------------------------------------------------------------------------
// Initial projection GEMM (f32 SIMD): h = relu(x @ Wp + bp); writes hA (f32)
// and hAb (bf16 row-major, the MFMA A-operand feed for layer 0).
// ---------------------------------------------------------------------------
__launch_bounds__(256)
__global__ void gemm0_kernel(const float* __restrict__ A, const float* __restrict__ B,
                             const float* __restrict__ bias, float* __restrict__ C,
                             unsigned* __restrict__ Cb) {
    constexpr int K = 64;
    __shared__ float Bs[K * 128];
    int t = threadIdx.x;
    const float4* B4 = (const float4*)B;
    float4* Bs4 = (float4*)Bs;
#pragma unroll
    for (int i = t; i < K * 32; i += 256) Bs4[i] = B4[i];
    __syncthreads();

    int c0 = (t & 15) * 8;
    int r0 = (t >> 4) * 4;
    int rbase = blockIdx.x * 64 + r0;

    float acc[4][8];
#pragma unroll
    for (int j = 0; j < 4; j++)
#pragma unroll
        for (int c = 0; c < 8; c++) acc[j][c] = 0.f;

    const float4* A4 = (const float4*)A;
    int rg[4];
#pragma unroll
    for (int j = 0; j < 4; j++) rg[j] = min(rbase + j, N_NODES - 1);

    for (int kk = 0; kk < K; kk += 4) {
        float4 av[4];
#pragma unroll
        for (int j = 0; j < 4; j++) av[j] = A4[(size_t)rg[j] * (K / 4) + (kk >> 2)];
        float a_arr[4][4];
#pragma unroll
        for (int j = 0; j < 4; j++) {
            a_arr[j][0] = av[j].x; a_arr[j][1] = av[j].y;
            a_arr[j][2] = av[j].z; a_arr[j][3] = av[j].w;
        }
#pragma unroll
        for (int jj = 0; jj < 4; jj++) {
            float4 b0 = Bs4[(kk + jj) * 32 + (c0 >> 2)];
            float4 b1 = Bs4[(kk + jj) * 32 + (c0 >> 2) + 1];
#pragma unroll
            for (int j = 0; j < 4; j++) {
                float a = a_arr[j][jj];
                acc[j][0] += a * b0.x; acc[j][1] += a * b0.y;
                acc[j][2] += a * b0.z; acc[j][3] += a * b0.w;
                acc[j][4] += a * b1.x; acc[j][5] += a * b1.y;
                acc[j][6] += a * b1.z; acc[j][7] += a * b1.w;
            }
        }
    }

#pragma unroll
    for (int j = 0; j < 4; j++) {
        int r = rbase + j;
        if (r < N_NODES) {
            float o[8];
#pragma unroll
            for (int c = 0; c < 8; c++) o[c] = fmaxf(acc[j][c] + bias[c0 + c], 0.f);
            ((float4*)(C + (size_t)r * 128 + c0))[0] = make_float4(o[0], o[1], o[2], o[3]);
            ((float4*)(C + (size_t)r * 128 + c0 + 4))[0] = make_float4(o[4], o[5], o[6], o[7]);
            uint4 pk;
            pk.x = bf16pair(o[0], o[1]); pk.y = bf16pair(o[2], o[3]);
            pk.z = bf16pair(o[4], o[5]); pk.w = bf16pair(o[6], o[7]);
            ((uint4*)(Cb + (size_t)r * 64 + (c0 >> 1)))[0] = pk;
        }
    }
}

// ---------------------------------------------------------------------------
// Layer projection GEMM via MFMA bf16: xp = hAb @ W_l. One wave = 16 rows x
// 128 cols (8 tiles of 16x16, K-loop 4 x 32). A from row-major bf16 hAb; B
// from pre-packed wb fragments (global, L1/L2-hot). Epilogue: per-wave LDS
// transpose of the C layout (col=lane&15, row=quad*4+reg), then lane=(row,h)
// computes both attention dots (no shuffles), packs bf16 row chunk to xpb.
// ---------------------------------------------------------------------------
__launch_bounds__(256)
__global__ void gemm_mfma_kernel(const unsigned short* __restrict__ hAb,
                                 const unsigned short* __restrict__ wb,
                                 const float* __restrict__ att_s,
                                 const float* __restrict__ att_d,
                                 unsigned* __restrict__ xpb,
                                 float* __restrict__ asrc, float* __restrict__ adst) {
    __shared__ float lds[4][16][129];
    int t = threadIdx.x;
    int w = t >> 6, lane = t & 63;
    int rbase = blockIdx.x * 64 + w * 16;
    int mrow = lane & 15, quad = lane >> 4;

    floatx4 acc[8];
#pragma unroll
    for (int nt = 0; nt < 8; nt++) acc[nt] = (floatx4){0.f, 0.f, 0.f, 0.f};

    int arow = min(rbase + mrow, N_NODES - 1);
    const short8* wb8 = (const short8*)wb;
#pragma unroll
    for (int kt = 0; kt < 4; kt++) {
        short8 afrag = *(const short8*)(hAb + (size_t)arow * 128 + kt * 32 + quad * 8);
#pragma unroll
        for (int nt = 0; nt < 8; nt++) {
            short8 bfrag = wb8[(kt * 8 + nt) * 64 + lane];
            acc[nt] = __builtin_amdgcn_mfma_f32_16x16x32_bf16(afrag, bfrag, acc[nt], 0, 0, 0);
        }
    }

    // C layout -> LDS (per-wave region; same-wave read below, no barrier)
#pragma unroll
    for (int nt = 0; nt < 8; nt++)
#pragma unroll
        for (int rr = 0; rr < 4; rr++)
            lds[w][quad * 4 + rr][nt * 16 + mrow] = acc[nt][rr];

    int row = lane >> 2, h = lane & 3;
    int r = rbase + row;
    float vals[32];
    float ps = 0.f, pd = 0.f;
#pragma unroll
    for (int c = 0; c < 32; c++) {
        float v = lds[w][row][h * 32 + c];
        vals[c] = v;
        ps += v * att_s[h * 32 + c];
        pd += v * att_d[h * 32 + c];
    }
    if (r < N_NODES) {
        unsigned* dstp = xpb + (size_t)r * 64 + h * 16;
#pragma unroll
        for (int qq = 0; qq < 4; qq++) {
            uint4 o;
            o.x = bf16pair(vals[qq * 8 + 0], vals[qq * 8 + 1]);
            o.y = bf16pair(vals[qq * 8 + 2], vals[qq * 8 + 3]);
            o.z = bf16pair(vals[qq * 8 + 4], vals[qq * 8 + 5]);
            o.w = bf16pair(vals[qq * 8 + 6], vals[qq * 8 + 7]);
            ((uint4*)dstp)[qq] = o;
        }
        asrc[r * 4 + h] = ps;
        adst[r * 4 + h] = pd;
    }
}

// ---------------------------------------------------------------------------
// Per-edge: ex = exp(leakyrelu(a_src+a_dst+a_edge)), scattered to CSR slot.
// ---------------------------------------------------------------------------
__launch_bounds__(256)
__global__ void edge_kernel(const int* __restrict__ src, const int* __restrict__ dst,
                            const float* __restrict__ ea, const float* __restrict__ asrc,
                            const float* __restrict__ adst, const float* __restrict__ wea,
                            const float* __restrict__ aloop, const int* __restrict__ epos,
                            float* __restrict__ exs) {
    int e = blockIdx.x * blockDim.x + threadIdx.x;
    if (e >= N_ETOT) return;
    int s, d;
    float ae0, ae1, ae2, ae3;
    if (e < N_EDGES) {
        s = src[e]; d = dst[e];
        ae0 = ae1 = ae2 = ae3 = 0.f;
        const float* er = ea + (size_t)e * ED;
#pragma unroll
        for (int dd = 0; dd < 12; dd++) {
            float v = er[dd];
            ae0 += v * wea[dd * 4 + 0];
            ae1 += v * wea[dd * 4 + 1];
            ae2 += v * wea[dd * 4 + 2];
            ae3 += v * wea[dd * 4 + 3];
        }
    } else {
        s = d = e - N_EDGES;
        ae0 = aloop[0]; ae1 = aloop[1]; ae2 = aloop[2]; ae3 = aloop[3];
    }
    float4 as = ((const float4*)asrc)[s];
    float4 ad = ((const float4*)adst)[d];
    float a0 = as.x + ad.x + ae0;
    float a1 = as.y + ad.y + ae1;
    float a2 = as.z + ad.z + ae2;
    float a3 = as.w + ad.w + ae3;
    a0 = (a0 > 0.f) ? a0 : 0.2f * a0;
    a1 = (a1 > 0.f) ? a1 : 0.2f * a1;
    a2 = (a2 > 0.f) ? a2 : 0.2f * a2;
    a3 = (a3 > 0.f) ? a3 : 0.2f * a3;
    float4 ex;
    ex.x = __expf(fminf(a0, 60.f));
    ex.y = __expf(fminf(a1, 60.f));
    ex.z = __expf(fminf(a2, 60.f));
    ex.w = __expf(fminf(a3, 60.f));
    ((float4*)exs)[epos[e]] = ex;
}

// ---------------------------------------------------------------------------
// Single-pass aggregation: one wave per node, QUARTER-WAVE (16 lanes) per
// edge. lane = 16*sub + sl: sub picks edge j+sub, sl covers channels
// 8*sl..8*sl+7 as uint4 (head h = sl>>2). One dwordx4 fetches 4 edges' rows;
// unroll x2 = 8 edges in flight. Reduce over sub via shfl_xor(16,32).
// ---------------------------------------------------------------------------
__launch_bounds__(256)
__global__ void node_kernel(const float* __restrict__ exs, const int* __restrict__ rowp,
                            const int* __restrict__ csr_src, const unsigned* __restrict__ xpb,
                            float* __restrict__ out) {
    int gw = (blockIdx.x * blockDim.x + threadIdx.x) >> 6;
    int lane = threadIdx.x & 63;
    if (gw >= N_NODES) return;
    int sub = lane >> 4;   // edge slot 0..3
    int sl  = lane & 15;   // channel octet
    int h   = sl >> 2;     // head
    int beg = rowp[gw], end = rowp[gw + 1];
    const float4* exs4 = (const float4*)exs;
    const uint4* xp4 = (const uint4*)xpb;   // 16 uint4 per 128-ch row

    float a[8];
#pragma unroll
    for (int c = 0; c < 8; c++) a[c] = 0.f;
    float den = 0.f;

    int j = beg + sub;
    for (; j + 4 < end; j += 8) {
        int s0 = csr_src[j];
        int s1 = csr_src[j + 4];
        float4 e0 = exs4[j];
        float4 e1 = exs4[j + 4];
        uint4 v0 = xp4[(size_t)s0 * 16 + sl];
        uint4 v1 = xp4[(size_t)s1 * 16 + sl];
        float ex0 = (h == 0) ? e0.x : (h == 1) ? e0.y : (h == 2) ? e0.z : e0.w;
        float ex1 = (h == 0) ? e1.x : (h == 1) ? e1.y : (h == 2) ? e1.z : e1.w;
        a[0] += ex0 * __uint_as_float(v0.x << 16);
        a[1] += ex0 * __uint_as_float(v0.x & 0xFFFF0000u);
        a[2] += ex0 * __uint_as_float(v0.y << 16);
        a[3] += ex0 * __uint_as_float(v0.y & 0xFFFF0000u);
        a[4] += ex0 * __uint_as_float(v0.z << 16);
        a[5] += ex0 * __uint_as_float(v0.z & 0xFFFF0000u);
        a[6] += ex0 * __uint_as_float(v0.w << 16);
        a[7] += ex0 * __uint_as_float(v0.w & 0xFFFF0000u);
        a[0] += ex1 * __uint_as_float(v1.x << 16);
        a[1] += ex1 * __uint_as_float(v1.x & 0xFFFF0000u);
        a[2] += ex1 * __uint_as_float(v1.y << 16);
        a[3] += ex1 * __uint_as_float(v1.y & 0xFFFF0000u);
        a[4] += ex1 * __uint_as_float(v1.z << 16);
        a[5] += ex1 * __uint_as_float(v1.z & 0xFFFF0000u);
        a[6] += ex1 * __uint_as_float(v1.w << 16);
        a[7] += ex1 * __uint_as_float(v1.w & 0xFFFF0000u);
        den += ex0 + ex1;
    }
    if (j < end) {
        int s0 = csr_src[j];
        float4 e0 = exs4[j];
        uint4 v0 = xp4[(size_t)s0 * 16 + sl];
        float ex0 = (h == 0) ? e0.x : (h == 1) ? e0.y : (h == 2) ? e0.z : e0.w;
        a[0] += ex0 * __uint_as_float(v0.x << 16);
        a[1] += ex0 * __uint_as_float(v0.x & 0xFFFF0000u);
        a[2] += ex0 * __uint_as_float(v0.y << 16);
        a[3] += ex0 * __uint_as_float(v0.y & 0xFFFF0000u);
        a[4] += ex0 * __uint_as_float(v0.z << 16);
        a[5] += ex0 * __uint_as_float(v0.z & 0xFFFF0000u);
        a[6] += ex0 * __uint_as_float(v0.w << 16);
        a[7] += ex0 * __uint_as_float(v0.w & 0xFFFF0000u);
        den += ex0;
    }
    // reduce over the 4 quarter-waves
#pragma unroll
    for (int c = 0; c < 8; c++) {
        a[c] += __shfl_xor(a[c], 16);
        a[c] += __shfl_xor(a[c], 32);
    }
    den += __shfl_xor(den, 16);
    den += __shfl_xor(den, 32);
    float inv = 1.0f / den;   // deg >= 1 (self loop)
    if (sub == 0) {
        float* op = out + (size_t)gw * 128 + sl * 8;
        ((float4*)op)[0] = make_float4(a[0] * inv, a[1] * inv, a[2] * inv, a[3] * inv);
        ((float4*)op)[1] = make_float4(a[4] * inv, a[5] * inv, a[6] * inv, a[7] * inv);
    }
}

// ---------------------------------------------------------------------------
// BatchNorm statistics + fused update (BN finalize in-block, relu, residual,
// and bf16 repack of the new h for the next layer's MFMA GEMM)
// ---------------------------------------------------------------------------
__launch_bounds__(256)
__global__ void bnstats_kernel(const float* __restrict__ h, float* __restrict__ bnsum,
                               float* __restrict__ bnsum2) {
    __shared__ float ls[256], ls2[256];
    int t = threadIdx.x;
    int c = t & 127, half = t >> 7;
    int r0 = blockIdx.x * 128;
    float s = 0.f, s2 = 0.f;
    int rend = min(r0 + 128, N_NODES);
    for (int r = r0 + half; r < rend; r += 2) {
        float v = h[(size_t)r * 128 + c];
        s += v; s2 += v * v;
    }
    ls[t] = s; ls2[t] = s2;
    __syncthreads();
    if (half == 0) {
        s += ls[t + 128]; s2 += ls2[t + 128];
        atomicAdd(&bnsum[c], s);
        atomicAdd(&bnsum2[c], s2);
    }
}

__launch_bounds__(256)
__global__ void update_kernel(const float* __restrict__ outb, const float* __restrict__ bnsum,
                              const float* __restrict__ bnsum2, const float* __restrict__ gamma,
                              const float* __restrict__ beta, const float* __restrict__ hA,
                              float* __restrict__ dst, unsigned* __restrict__ dstb,
                              int add_res) {
    __shared__ float sc_s[128], sh_s[128];
    int t = threadIdx.x;
    if (t < 128) {
        float mu = bnsum[t] / (float)N_NODES;
        float var = bnsum2[t] / (float)N_NODES - mu * mu;
        float inv = rsqrtf(var + BN_EPS);
        float g = gamma[t] * inv;
        sc_s[t] = g;
        sh_s[t] = beta[t] - mu * g;
    }
    __syncthreads();
    int i = blockIdx.x * blockDim.x + t;
    if (i >= N_NODES * 32) return;
    int c4 = (i & 31) * 4;
    float4 o = ((const float4*)outb)[i];
    float4 v;
    v.x = fmaxf(o.x * sc_s[c4 + 0] + sh_s[c4 + 0], 0.f);
    v.y = fmaxf(o.y * sc_s[c4 + 1] + sh_s[c4 + 1], 0.f);
    v.z = fmaxf(o.z * sc_s[c4 + 2] + sh_s[c4 + 2], 0.f);
    v.w = fmaxf(o.w * sc_s[c4 + 3] + sh_s[c4 + 3], 0.f);
    if (add_res) {
        float4 hh = ((const float4*)hA)[i];
        v.x += hh.x; v.y += hh.y; v.z += hh.z; v.w += hh.w;
    }
    ((float4*)dst)[i] = v;
    ((uint2*)dstb)[i] = make_uint2(bf16pair(v.x, v.y), bf16pair(v.z, v.w));
}

// ---------------------------------------------------------------------------
extern "C" void kernel_launch(void* const* d_in, const int* in_sizes, int n_in,
                              void* d_out, int out_size, void* d_ws, size_t ws_size,
                              hipStream_t stream) {
    const float* x          = (const float*)d_in[0];
    const int*   edge_index = (const int*)d_in[1];
    const float* edge_attr  = (const float*)d_in[2];
    const float* Wp         = (const float*)d_in[3];
    const float* bp         = (const float*)d_in[4];
    const float* W          = (const float*)d_in[5];
    const float* We         = (const float*)d_in[6];
    const float* att_src    = (const float*)d_in[7];
    const float* att_dst    = (const float*)d_in[8];
    const float* att_edge   = (const float*)d_in[9];
    // d_in[10] bias: absorbed exactly by training-mode BN -> skipped
    const float* gamma      = (const float*)d_in[11];
    const float* beta       = (const float*)d_in[12];
    float* outp = (float*)d_out;

    const int* ei_src = edge_index;
    const int* ei_dst = edge_index + N_EDGES;

    char* p = (char*)d_ws;
    auto alloc = [&](size_t nbytes) {
        char* r = p;
        p += (nbytes + 255) & ~(size_t)255;
        return r;
    };
    // zero-initialized region: hist | easum | bnsum(4 layers x 256)
    int*   hist     = (int*)alloc((size_t)N_NODES * 4);
    float* easum    = (float*)alloc(16 * 4);
    float* bnsumall = (float*)alloc((size_t)LAYERS * 256 * 4);
    size_t zero_bytes = (char*)(bnsumall + LAYERS * 256) - (char*)hist;

    float* hA       = (float*)alloc((size_t)N_NODES * 128 * 4);
    unsigned* hAb   = (unsigned*)alloc((size_t)N_NODES * 64 * 4);   // bf16x2, GEMM A feed
    unsigned* xpb   = (unsigned*)alloc((size_t)N_NODES * 64 * 4);   // bf16x2, gather payload
    float* outb     = (float*)alloc((size_t)N_NODES * 128 * 4);
    float* exs      = (float*)alloc((size_t)N_ETOT * 4 * 4);
    float* asrc     = (float*)alloc((size_t)N_NODES * 4 * 4);
    float* adst     = (float*)alloc((size_t)N_NODES * 4 * 4);
    float* wea_all  = (float*)alloc((LAYERS * 48 + 16) * 4);
    float* aloop    = wea_all + LAYERS * 48;
    unsigned short* wb = (unsigned short*)alloc((size_t)LAYERS * 16384 * 2);
    int* rowp       = (int*)alloc(((size_t)N_NODES + 1) * 4);
    int* cursor     = (int*)alloc((size_t)N_NODES * 4);
    int* epos       = (int*)alloc((size_t)N_ETOT * 4);
    int* csr_src    = (int*)alloc((size_t)N_ETOT * 4);
    int* bsum       = (int*)alloc(256 * 4);
    int* boff       = (int*)alloc(256 * 4);

    const int EB = (N_ETOT + 255) / 256;

    (void)hipMemsetAsync(hist, 0, zero_bytes, stream);

    // ---- CSR build (graph fixed across layers) ----
    hist_kernel<<<EB, 256, 0, stream>>>(ei_dst, hist);
    blocksum_kernel<<<SCAN_BLK, 256, 0, stream>>>(hist, bsum);
    bscan_kernel<<<1, 256, 0, stream>>>(bsum, boff, rowp);
    rowp_kernel<<<SCAN_BLK, 256, 0, stream>>>(hist, boff, rowp, cursor);
    scatter_kernel<<<EB, 256, 0, stream>>>(ei_src, ei_dst, cursor, epos, csr_src);

    // ---- edge-attr mean + folded matrices + W pre-pack (all layers) ----
    eamean_kernel<<<256, 256, 0, stream>>>(edge_attr, easum);
    prep_kernel<<<1, 256, 0, stream>>>(easum, We, att_edge, wea_all, aloop);
    packW_kernel<<<(LAYERS * HID * HID + 255) / 256, 256, 0, stream>>>(W, wb);

    // ---- initial projection (f32 SIMD, bias+relu, dual f32/bf16 store) ----
    gemm0_kernel<<<(N_NODES + 63) / 64, 256, 0, stream>>>(x, Wp, bp, hA, hAb);

    for (int l = 0; l < LAYERS; l++) {
        float* bnsum  = bnsumall + l * 256;
        float* bnsum2 = bnsum + 128;
        gemm_mfma_kernel<<<(N_NODES + 63) / 64, 256, 0, stream>>>(
            (const unsigned short*)hAb, wb + (size_t)l * 16384,
            att_src + l * 128, att_dst + l * 128, xpb, asrc, adst);
        edge_kernel<<<EB, 256, 0, stream>>>(ei_src, ei_dst, edge_attr, asrc, adst,
                                            wea_all + l * 48, aloop + l * 4, epos, exs);
        node_kernel<<<(N_NODES + 3) / 4, 256, 0, stream>>>(exs, rowp, csr_src, xpb, outb);
        bnstats_kernel<<<(N_NODES + 127) / 128, 256, 0, stream>>>(outb, bnsum, bnsum2);
        float* dst = (l == LAYERS - 1) ? outp : hA;
        update_kernel<<<(N_NODES * 32 + 255) / 256, 256, 0, stream>>>(
            outb, bnsum, bnsum2, gamma + l * 128, beta + l * 128, hA, dst, hAb,
            (l > 0) ? 1 : 0);
    }
}